// Round 7
// baseline (707.640 us; speedup 1.0000x reference)
//
#include <hip/hip_runtime.h>
#include <hip/hip_bf16.h>
#include <math.h>

#define NH 8
#define DH 40
#define CCH 320
#define SCALE 0.15811388300841897f

typedef __attribute__((ext_vector_type(8))) short short8;
typedef __attribute__((ext_vector_type(4))) float float4v;

static __device__ __forceinline__ unsigned short f2bf(float x) {
  __hip_bfloat16 t = __float2bfloat16(x);
  return *reinterpret_cast<unsigned short*>(&t);
}

// ---------------- GroupNorm (32 groups, eps 1e-6) + transpose to (B,HW,C), bf16 out ----------------
__global__ __launch_bounds__(256) void gn_kernel(const float* __restrict__ x,
                                                 const float* __restrict__ w,
                                                 const float* __restrict__ b,
                                                 unsigned short* __restrict__ out) {
  int batch = blockIdx.x >> 5;
  int g = blockIdx.x & 31;
  const int CPG = 10;
  const float* xp = x + ((size_t)batch * CCH + g * CPG) * 1024;
  float s = 0.f, ss = 0.f;
  for (int i = threadIdx.x; i < CPG * 1024; i += 256) { float v = xp[i]; s += v; ss += v * v; }
  __shared__ float r1[256], r2[256];
  r1[threadIdx.x] = s; r2[threadIdx.x] = ss; __syncthreads();
  for (int off = 128; off > 0; off >>= 1) {
    if (threadIdx.x < off) { r1[threadIdx.x] += r1[threadIdx.x + off]; r2[threadIdx.x] += r2[threadIdx.x + off]; }
    __syncthreads();
  }
  float mu = r1[0] * (1.f / 10240.f);
  float var = r2[0] * (1.f / 10240.f) - mu * mu;
  float inv = rsqrtf(var + 1e-6f);
  for (int i = threadIdx.x; i < CPG * 1024; i += 256) {
    int ci = i >> 10; int hw = i & 1023; int c = g * CPG + ci;
    float v = (xp[i] - mu) * inv * w[c] + b[c];
    out[((size_t)batch * 1024 + hw) * CCH + c] = f2bf(v);
  }
}

// ---------------- LayerNorm over C=320, eps 1e-5, one wave per row, bf16 out ----------------
__global__ __launch_bounds__(64) void ln_kernel(const float* __restrict__ x,
                                                const float* __restrict__ w,
                                                const float* __restrict__ b,
                                                unsigned short* __restrict__ out, int M) {
  int row = blockIdx.x;
  if (row >= M) return;
  const float* xp = x + (size_t)row * CCH;
  int lane = threadIdx.x;
  float v[5]; float s = 0.f;
#pragma unroll
  for (int i = 0; i < 5; i++) { v[i] = xp[lane + 64 * i]; s += v[i]; }
#pragma unroll
  for (int o = 32; o > 0; o >>= 1) s += __shfl_xor(s, o);
  float mu = s * (1.f / 320.f);
  float ss = 0.f;
#pragma unroll
  for (int i = 0; i < 5; i++) { float d = v[i] - mu; ss += d * d; }
#pragma unroll
  for (int o = 32; o > 0; o >>= 1) ss += __shfl_xor(ss, o);
  float inv = rsqrtf(ss * (1.f / 320.f) + 1e-5f);
  unsigned short* op = out + (size_t)row * CCH;
#pragma unroll
  for (int i = 0; i < 5; i++) { int c = lane + 64 * i; op[c] = f2bf((v[i] - mu) * inv * w[c] + b[c]); }
}

// ---------------- weight transpose+convert: W(KxN f32) -> Wt(NxK bf16) ----------------
struct WTab {
  const float* src[16];
  unsigned short* dst[16];
  int Kd[16];
  int Nd[16];
  int tstart[17];
};
__global__ __launch_bounds__(256) void wconv_kernel(WTab t) {
  __shared__ float tile[32][33];
  int gid = blockIdx.x;
  int w = 0;
  while (w < 15 && gid >= t.tstart[w + 1]) w++;
  int local = gid - t.tstart[w];
  int K = t.Kd[w], N = t.Nd[w];
  int ntx = (N + 31) >> 5;
  int bx = local % ntx, by = local / ntx;
  int nb = bx * 32, kb = by * 32;
  const float* src = t.src[w];
  unsigned short* dst = t.dst[w];
  int tx = threadIdx.x & 31, ty = threadIdx.x >> 5;
  for (int i = ty; i < 32; i += 8) {
    int k = kb + i, n = nb + tx;
    tile[i][tx] = (k < K && n < N) ? src[(size_t)k * N + n] : 0.f;
  }
  __syncthreads();
  for (int i = ty; i < 32; i += 8) {
    int n = nb + i, k = kb + tx;
    if (n < N && k < K) dst[(size_t)n * K + k] = f2bf(tile[tx][i]);
  }
}

// ---------------- f32 -> bf16 elementwise convert ----------------
__global__ __launch_bounds__(256) void conv_kernel(const float* __restrict__ src,
                                                   unsigned short* __restrict__ dst, int n) {
  int i = blockIdx.x * 256 + threadIdx.x;
  if (i < n) dst[i] = f2bf(src[i]);
}

// ---------------- bf16 MFMA GEMM 128x128: out = [res +] A @ Bt^T [+ bias] ----------------
__global__ __launch_bounds__(256) void mgemm_kernel(const unsigned short* __restrict__ A,
                                                    const unsigned short* __restrict__ Bt,
                                                    const float* __restrict__ bias,
                                                    const float* __restrict__ res,
                                                    void* __restrict__ outp,
                                                    int M, int N, int K, int obf) {
  __shared__ unsigned short As[128][40];
  __shared__ unsigned short Bs[128][40];
  int tid = threadIdx.x;
  int lane = tid & 63;
  int wave = tid >> 6;
  int wm = (wave & 1) * 64;
  int wn = (wave >> 1) * 64;
  int m0 = blockIdx.y * 128;
  int n0 = blockIdx.x * 128;
  float4v acc[4][4];
  float4v zero = {0.f, 0.f, 0.f, 0.f};
#pragma unroll
  for (int i = 0; i < 4; i++)
#pragma unroll
    for (int j = 0; j < 4; j++) acc[i][j] = zero;
  int r0 = tid >> 2;
  int kc = (tid & 3) * 8;
  short8 vzero = {0, 0, 0, 0, 0, 0, 0, 0};
  int fr = lane & 15;
  int kq = (lane >> 4) * 8;
  for (int k0 = 0; k0 < K; k0 += 32) {
#pragma unroll
    for (int i = 0; i < 2; i++) {
      int row = r0 + i * 64;
      int m = m0 + row;
      short8 av = vzero;
      if (m < M) av = *(const short8*)(A + (size_t)m * K + k0 + kc);
      *(short8*)&As[row][kc] = av;
      int n = n0 + row;
      short8 bv = vzero;
      if (n < N) bv = *(const short8*)(Bt + (size_t)n * K + k0 + kc);
      *(short8*)&Bs[row][kc] = bv;
    }
    __syncthreads();
    short8 af[4], bfr[4];
#pragma unroll
    for (int i = 0; i < 4; i++) af[i] = *(short8*)&As[wm + i * 16 + fr][kq];
#pragma unroll
    for (int j = 0; j < 4; j++) bfr[j] = *(short8*)&Bs[wn + j * 16 + fr][kq];
#pragma unroll
    for (int i = 0; i < 4; i++)
#pragma unroll
      for (int j = 0; j < 4; j++)
        acc[i][j] = __builtin_amdgcn_mfma_f32_16x16x32_bf16(af[i], bfr[j], acc[i][j], 0, 0, 0);
    __syncthreads();
  }
#pragma unroll
  for (int i = 0; i < 4; i++) {
    int mbase = m0 + wm + i * 16 + (lane >> 4) * 4;
#pragma unroll
    for (int j = 0; j < 4; j++) {
      int n = n0 + wn + j * 16 + (lane & 15);
      if (n >= N) continue;
      float bv = bias ? bias[n] : 0.f;
#pragma unroll
      for (int r = 0; r < 4; r++) {
        int m = mbase + r;
        if (m < M) {
          float v = acc[i][j][r] + bv;
          if (res) v += res[(size_t)m * N + n];
          if (obf) ((unsigned short*)outp)[(size_t)m * N + n] = f2bf(v);
          else ((float*)outp)[(size_t)m * N + n] = v;
        }
      }
    }
  }
}

// ---------------- bf16 MFMA GEMM 64x64 (for small N: more blocks, less VGPR) ----------------
__global__ __launch_bounds__(256) void mgemm64_kernel(const unsigned short* __restrict__ A,
                                                      const unsigned short* __restrict__ Bt,
                                                      const float* __restrict__ bias,
                                                      const float* __restrict__ res,
                                                      void* __restrict__ outp,
                                                      int M, int N, int K, int obf) {
  __shared__ unsigned short As[64][40];
  __shared__ unsigned short Bs[64][40];
  int tid = threadIdx.x;
  int lane = tid & 63;
  int wv = tid >> 6;
  int quad = lane >> 4;
  int col = lane & 15;
  int m0 = blockIdx.y * 64;
  int n0 = blockIdx.x * 64;
  float4v acc[4];
  float4v zero = {0.f, 0.f, 0.f, 0.f};
#pragma unroll
  for (int j = 0; j < 4; j++) acc[j] = zero;
  int r0 = tid >> 2;
  int kc = (tid & 3) * 8;
  int kq = quad * 8;
  short8 vzero = {0, 0, 0, 0, 0, 0, 0, 0};
  for (int k0 = 0; k0 < K; k0 += 32) {
    int m = m0 + r0;
    short8 av = vzero;
    if (m < M) av = *(const short8*)(A + (size_t)m * K + k0 + kc);
    *(short8*)&As[r0][kc] = av;
    int n = n0 + r0;
    short8 bv = vzero;
    if (n < N) bv = *(const short8*)(Bt + (size_t)n * K + k0 + kc);
    *(short8*)&Bs[r0][kc] = bv;
    __syncthreads();
    short8 af = *(short8*)&As[wv * 16 + col][kq];
#pragma unroll
    for (int j = 0; j < 4; j++) {
      short8 bfr = *(short8*)&Bs[j * 16 + col][kq];
      acc[j] = __builtin_amdgcn_mfma_f32_16x16x32_bf16(af, bfr, acc[j], 0, 0, 0);
    }
    __syncthreads();
  }
#pragma unroll
  for (int j = 0; j < 4; j++) {
    int n = n0 + j * 16 + col;
    if (n >= N) continue;
    float bv = bias ? bias[n] : 0.f;
#pragma unroll
    for (int r = 0; r < 4; r++) {
      int m = m0 + wv * 16 + quad * 4 + r;
      if (m < M) {
        float v = acc[j][r] + bv;
        if (res) v += res[(size_t)m * N + n];
        if (obf) ((unsigned short*)outp)[(size_t)m * N + n] = f2bf(v);
        else ((float*)outp)[(size_t)m * N + n] = v;
      }
    }
  }
}

// ---------------- MFMA flash attention: S=1024 keys, bf16 in/out ----------------
// grid: B*NH*16 blocks (Q-tile=64) of 256 threads (4 waves, 16 Q-rows each).
// V staged TRANSPOSED (Vt[d][key], stride 72) so PV B-frags are contiguous b128.
#define VSTR 72
__global__ __launch_bounds__(256) void mfattn_kernel(const unsigned short* __restrict__ qp, int qstr,
                                                     const unsigned short* __restrict__ kp, int kstr,
                                                     const unsigned short* __restrict__ vp, int vstr,
                                                     const float* __restrict__ bias,
                                                     unsigned short* __restrict__ op, int ostr) {
  __shared__ unsigned short Ks[64 * 56];
  __shared__ unsigned short Vt[48 * VSTR];
  __shared__ unsigned short Ps[4][16 * 72];
  int tid = threadIdx.x;
  int lane = tid & 63;
  int wv = tid >> 6;
  int quad = lane >> 4;
  int col = lane & 15;
  int bid = blockIdx.x;
  int qt = bid & 15;
  int h = (bid >> 4) & 7;
  int b = bid >> 7;

  short8 zero8 = {0, 0, 0, 0, 0, 0, 0, 0};
  int qrow = qt * 64 + wv * 16 + col;
  const unsigned short* qbase = qp + (size_t)(b * 1024 + qrow) * qstr + h * DH;
  short8 qf0 = *(const short8*)(qbase + quad * 8);
  short8 qf1 = (quad == 0) ? *(const short8*)(qbase + 32) : zero8;

  float4v Oacc[3];
  float4v fzero = {0.f, 0.f, 0.f, 0.f};
  Oacc[0] = fzero; Oacc[1] = fzero; Oacc[2] = fzero;
  float mr[4] = {-3.4e38f, -3.4e38f, -3.4e38f, -3.4e38f};
  float lr[4] = {0.f, 0.f, 0.f, 0.f};

  for (int kt = 0; kt < 16; kt++) {
    int kb = kt * 64;
    __syncthreads();
    // K: key-major, vector writes
    for (int u = tid; u < 384; u += 256) {
      int key = u / 6, s = u - key * 6;
      short8 kv8 = zero8;
      if (s < 5) kv8 = *(const short8*)(kp + (size_t)(b * 1024 + kb + key) * kstr + h * DH + s * 8);
      *(short8*)&Ks[key * 56 + s * 8] = kv8;
    }
    // V: s-major transpose staging -> Vt[d][key] (write banks = key/2: conflict-free)
    for (int u = tid; u < 384; u += 256) {
      int s = u >> 6, key = u & 63;
      short8 vv8 = zero8;
      if (s < 5) vv8 = *(const short8*)(vp + (size_t)(b * 1024 + kb + key) * vstr + h * DH + s * 8);
#pragma unroll
      for (int j = 0; j < 8; j++) Vt[(s * 8 + j) * VSTR + key] = (unsigned short)vv8[j];
    }
    __syncthreads();

    float4v sf[4];
#pragma unroll
    for (int jb = 0; jb < 4; jb++) {
      const unsigned short* krow = &Ks[(jb * 16 + col) * 56];
      short8 bk0 = *(const short8*)(krow + quad * 8);
      short8 bk1 = (quad == 0) ? *(const short8*)(krow + 32) : zero8;
      float4v s = fzero;
      s = __builtin_amdgcn_mfma_f32_16x16x32_bf16(qf0, bk0, s, 0, 0, 0);
      s = __builtin_amdgcn_mfma_f32_16x16x32_bf16(qf1, bk1, s, 0, 0, 0);
      float bv = bias ? bias[b * 1024 + kb + jb * 16 + col] : 0.f;
#pragma unroll
      for (int r = 0; r < 4; r++) s[r] = s[r] * SCALE + bv;
      sf[jb] = s;
    }
    float tmax[4];
#pragma unroll
    for (int r = 0; r < 4; r++) {
      float t = fmaxf(fmaxf(sf[0][r], sf[1][r]), fmaxf(sf[2][r], sf[3][r]));
#pragma unroll
      for (int o = 1; o < 16; o <<= 1) t = fmaxf(t, __shfl_xor(t, o));
      tmax[r] = t;
    }
    float al[4];
#pragma unroll
    for (int r = 0; r < 4; r++) {
      float mnew = fmaxf(mr[r], tmax[r]);
      al[r] = __expf(mr[r] - mnew);
      mr[r] = mnew;
      lr[r] *= al[r];
    }
#pragma unroll
    for (int nb = 0; nb < 3; nb++)
#pragma unroll
      for (int r = 0; r < 4; r++) Oacc[nb][r] *= al[r];
    float rs[4] = {0.f, 0.f, 0.f, 0.f};
#pragma unroll
    for (int jb = 0; jb < 4; jb++) {
#pragma unroll
      for (int r = 0; r < 4; r++) {
        float p = __expf(sf[jb][r] - mr[r]);
        rs[r] += p;
        Ps[wv][(quad * 4 + r) * 72 + jb * 16 + col] = f2bf(p);
      }
    }
#pragma unroll
    for (int r = 0; r < 4; r++) {
      float t = rs[r];
#pragma unroll
      for (int o = 1; o < 16; o <<= 1) t += __shfl_xor(t, o);
      lr[r] += t;
    }
    // O += P @ V : B-frag now one contiguous b128 from Vt
#pragma unroll
    for (int kc = 0; kc < 2; kc++) {
      int koff = kc * 32 + quad * 8;
      short8 pa = *(const short8*)&Ps[wv][col * 72 + koff];
#pragma unroll
      for (int nb = 0; nb < 3; nb++) {
        short8 vb = *(const short8*)&Vt[(nb * 16 + col) * VSTR + koff];
        Oacc[nb] = __builtin_amdgcn_mfma_f32_16x16x32_bf16(pa, vb, Oacc[nb], 0, 0, 0);
      }
    }
  }
#pragma unroll
  for (int r = 0; r < 4; r++) {
    float inv = 1.f / lr[r];
    int qo = qt * 64 + wv * 16 + quad * 4 + r;
    unsigned short* orow = op + (size_t)(b * 1024 + qo) * ostr + h * DH;
#pragma unroll
    for (int nb = 0; nb < 3; nb++) {
      int d = nb * 16 + col;
      if (d < DH) orow[d] = f2bf(Oacc[nb][r] * inv);
    }
  }
}

// ---------------- MFMA cross-attention Lk=77 (bf16 in, bf16 out, f32 probs) ----------------
// V staged transposed: Vt[d][key], 96 padded keys, stride 104.
#define CVSTR 104
__global__ __launch_bounds__(256) void cattnm_kernel(const unsigned short* __restrict__ qp,
                                                     const unsigned short* __restrict__ kvp,
                                                     unsigned short* __restrict__ op,
                                                     float* __restrict__ probs) {
  __shared__ unsigned short Ks[80 * 56];
  __shared__ unsigned short Vt[48 * CVSTR];
  __shared__ unsigned short Ps[4][16 * 104];
  int tid = threadIdx.x;
  int lane = tid & 63;
  int wv = tid >> 6;
  int quad = lane >> 4;
  int col = lane & 15;
  int bid = blockIdx.x;
  int qt = bid & 15;
  int h = (bid >> 4) & 7;
  int b = bid >> 7;

  short8 zero8 = {0, 0, 0, 0, 0, 0, 0, 0};
  // K: 80 rows key-major
  for (int u = tid; u < 480; u += 256) {
    int key = u / 6, s = u - key * 6;
    short8 v8 = zero8;
    if (s < 5 && key < 77) v8 = *(const short8*)(kvp + (size_t)(b * 77 + key) * 640 + h * DH + s * 8);
    *(short8*)&Ks[key * 56 + s * 8] = v8;
  }
  // V: s-major transpose, 96 keys
  for (int u = tid; u < 576; u += 256) {
    int s = u / 96, key = u - s * 96;
    short8 v8 = zero8;
    if (s < 5 && key < 77) v8 = *(const short8*)(kvp + (size_t)(b * 77 + key) * 640 + 320 + h * DH + s * 8);
#pragma unroll
    for (int j = 0; j < 8; j++) Vt[(s * 8 + j) * CVSTR + key] = (unsigned short)v8[j];
  }
  int qrow = qt * 64 + wv * 16 + col;
  const unsigned short* qbase = qp + (size_t)(b * 1024 + qrow) * CCH + h * DH;
  short8 qf0 = *(const short8*)(qbase + quad * 8);
  short8 qf1 = (quad == 0) ? *(const short8*)(qbase + 32) : zero8;
  __syncthreads();

  float4v fzero = {0.f, 0.f, 0.f, 0.f};
  float4v sf[5];
#pragma unroll
  for (int jb = 0; jb < 5; jb++) {
    const unsigned short* krow = &Ks[(jb * 16 + col) * 56];
    short8 bk0 = *(const short8*)(krow + quad * 8);
    short8 bk1 = (quad == 0) ? *(const short8*)(krow + 32) : zero8;
    float4v s = fzero;
    s = __builtin_amdgcn_mfma_f32_16x16x32_bf16(qf0, bk0, s, 0, 0, 0);
    s = __builtin_amdgcn_mfma_f32_16x16x32_bf16(qf1, bk1, s, 0, 0, 0);
    int key = jb * 16 + col;
    float msk = (key < 77) ? 0.f : -3.4e38f;
#pragma unroll
    for (int r = 0; r < 4; r++) s[r] = s[r] * SCALE + msk;
    sf[jb] = s;
  }
  float inv[4];
#pragma unroll
  for (int r = 0; r < 4; r++) {
    float t = sf[0][r];
#pragma unroll
    for (int jb = 1; jb < 5; jb++) t = fmaxf(t, sf[jb][r]);
#pragma unroll
    for (int o = 1; o < 16; o <<= 1) t = fmaxf(t, __shfl_xor(t, o));
    float sum = 0.f;
#pragma unroll
    for (int jb = 0; jb < 5; jb++) { float e = __expf(sf[jb][r] - t); sf[jb][r] = e; sum += e; }
#pragma unroll
    for (int o = 1; o < 16; o <<= 1) sum += __shfl_xor(sum, o);
    inv[r] = 1.f / sum;
  }
#pragma unroll
  for (int jb = 0; jb < 5; jb++) {
    int key = jb * 16 + col;
#pragma unroll
    for (int r = 0; r < 4; r++) {
      float p = sf[jb][r] * inv[r];
      Ps[wv][(quad * 4 + r) * 104 + jb * 16 + col] = f2bf(p);
      if (key < 77) {
        int row = qt * 64 + wv * 16 + quad * 4 + r;
        probs[((size_t)(b * NH + h) * 1024 + row) * 77 + key] = p;
      }
    }
  }
  float4v Oacc[3];
  Oacc[0] = fzero; Oacc[1] = fzero; Oacc[2] = fzero;
#pragma unroll
  for (int kc = 0; kc < 3; kc++) {
    int koff = kc * 32 + quad * 8;
    short8 pa = (koff < 80) ? *(const short8*)&Ps[wv][col * 104 + koff] : zero8;
#pragma unroll
    for (int nb = 0; nb < 3; nb++) {
      short8 vb = *(const short8*)&Vt[(nb * 16 + col) * CVSTR + koff];
      Oacc[nb] = __builtin_amdgcn_mfma_f32_16x16x32_bf16(pa, vb, Oacc[nb], 0, 0, 0);
    }
  }
#pragma unroll
  for (int r = 0; r < 4; r++) {
    int qo = qt * 64 + wv * 16 + quad * 4 + r;
    unsigned short* orow = op + (size_t)(b * 1024 + qo) * CCH + h * DH;
#pragma unroll
    for (int nb = 0; nb < 3; nb++) {
      int d = nb * 16 + col;
      if (d < DH) orow[d] = f2bf(Oacc[nb][r]);
    }
  }
}

// ---------------- geglu: act = a * gelu_tanh(g), bf16 out ----------------
__global__ __launch_bounds__(256) void geglu_kernel(const float* __restrict__ ff,
                                                    unsigned short* __restrict__ act, int M) {
  int idx = blockIdx.x * 256 + threadIdx.x;
  if (idx >= M * 1280) return;
  int m = idx / 1280; int j = idx - m * 1280;
  float a = ff[(size_t)m * 2560 + j];
  float g = ff[(size_t)m * 2560 + 1280 + j];
  float t = tanhf(0.7978845608028654f * (g + 0.044715f * g * g * g));
  act[idx] = f2bf(a * (0.5f * g * (1.f + t)));
}

// ---------------- extract attn_ph / attn_eot from p2 (B,8,1024,77) ----------------
__global__ __launch_bounds__(256) void extract_kernel(const float* __restrict__ p2,
                                                      const int* __restrict__ phb, const int* __restrict__ pht,
                                                      const int* __restrict__ eob, const int* __restrict__ eot,
                                                      float* __restrict__ aph, float* __restrict__ aeo) {
  int idx = blockIdx.x * 256 + threadIdx.x;
  if (idx >= 2048) return;
  int i = idx >> 10, q = idx & 1023;
  int pb = phb[i], pt = pht[i], eb = eob[i], et = eot[i];
  float s1 = 0.f, s2 = 0.f;
#pragma unroll
  for (int hh = 0; hh < NH; hh++) {
    s1 += p2[(((size_t)(2 + pb) * NH + hh) * 1024 + q) * 77 + pt];
    s2 += p2[(((size_t)(2 + eb) * NH + hh) * 1024 + q) * 77 + et];
  }
  aph[idx] = s1 * 0.125f;
  aeo[idx] = s2 * 0.125f;
}

// ---------------- loss_reg ----------------
__global__ __launch_bounds__(256) void loss_kernel(const float* __restrict__ ph,
                                                   const float* __restrict__ eo,
                                                   float* __restrict__ out) {
  __shared__ float red[256];
  int tid = threadIdx.x;
  float total = 0.f;
  for (int i = 0; i < 2; i++) {
    float mp = -3.4e38f, me = -3.4e38f;
    for (int q = tid; q < 1024; q += 256) { mp = fmaxf(mp, ph[i * 1024 + q]); me = fmaxf(me, eo[i * 1024 + q]); }
    red[tid] = mp; __syncthreads();
    for (int o = 128; o > 0; o >>= 1) { if (tid < o) red[tid] = fmaxf(red[tid], red[tid + o]); __syncthreads(); }
    mp = red[0]; __syncthreads();
    red[tid] = me; __syncthreads();
    for (int o = 128; o > 0; o >>= 1) { if (tid < o) red[tid] = fmaxf(red[tid], red[tid + o]); __syncthreads(); }
    me = red[0]; __syncthreads();
    float part = 0.f;
    for (int q = tid; q < 1024; q += 256) {
      float d = ph[i * 1024 + q] / mp - eo[i * 1024 + q] / me;
      part += d * d;
    }
    red[tid] = part; __syncthreads();
    for (int o = 128; o > 0; o >>= 1) { if (tid < o) red[tid] += red[tid + o]; __syncthreads(); }
    total += red[0]; __syncthreads();
  }
  if (tid == 0) out[0] = total * (1.f / 2048.f);
}

// ---------------- otsu per row of 1024 ----------------
__global__ __launch_bounds__(256) void otsu_kernel(const float* __restrict__ mrow,
                                                   float* __restrict__ mask) {
  __shared__ float xs[1024];
  __shared__ float red[256];
  __shared__ float cl[10], sl[10];
  __shared__ float shthr;
  int i = blockIdx.x, tid = threadIdx.x;
  const float* mp = mrow + i * 1024;
  for (int q = tid; q < 1024; q += 256) xs[q] = mp[q];
  __syncthreads();
  float mn = 3.4e38f, mx = -3.4e38f;
  for (int q = tid; q < 1024; q += 256) { mn = fminf(mn, xs[q]); mx = fmaxf(mx, xs[q]); }
  red[tid] = mn; __syncthreads();
  for (int o = 128; o > 0; o >>= 1) { if (tid < o) red[tid] = fminf(red[tid], red[tid + o]); __syncthreads(); }
  mn = red[0]; __syncthreads();
  red[tid] = mx; __syncthreads();
  for (int o = 128; o > 0; o >>= 1) { if (tid < o) red[tid] = fmaxf(red[tid], red[tid + o]); __syncthreads(); }
  mx = red[0]; __syncthreads();
  float inv = 1.f / (mx - mn);
  for (int q = tid; q < 1024; q += 256) xs[q] = (xs[q] - mn) * inv;
  __syncthreads();
  float t0 = 0.f;
  for (int q = tid; q < 1024; q += 256) t0 += xs[q];
  red[tid] = t0; __syncthreads();
  for (int o = 128; o > 0; o >>= 1) { if (tid < o) red[tid] += red[tid + o]; __syncthreads(); }
  float total = red[0]; __syncthreads();
  for (int t = 0; t < 10; t++) {
    float th = t * 0.1f;
    float c = 0.f, s = 0.f;
    for (int q = tid; q < 1024; q += 256) { float v = xs[q]; if (v < th) { c += 1.f; s += v; } }
    red[tid] = c; __syncthreads();
    for (int o = 128; o > 0; o >>= 1) { if (tid < o) red[tid] += red[tid + o]; __syncthreads(); }
    if (tid == 0) cl[t] = red[0];
    __syncthreads();
    red[tid] = s; __syncthreads();
    for (int o = 128; o > 0; o >>= 1) { if (tid < o) red[tid] += red[tid + o]; __syncthreads(); }
    if (tid == 0) sl[t] = red[0];
    __syncthreads();
  }
  if (tid == 0) {
    float gmax = -3.4e38f; int best = 0;
    for (int t = 0; t < 10; t++) {
      float c_low = cl[t], c_high = 1024.f - c_low;
      float g;
      if (c_low > 0.f && c_high > 0.f) {
        float mu_l = sl[t] / c_low;
        float mu_h = (total - sl[t]) / c_high;
        float d = mu_l - mu_h;
        g = (c_low * (1.f / 1024.f)) * (c_high * (1.f / 1024.f)) * d * d;
      } else g = -3.4e38f;
      if (g > gmax) { gmax = g; best = t; }
    }
    shthr = (gmax > 0.f) ? best * 0.1f : 0.f;
  }
  __syncthreads();
  float thr = shthr;
  for (int q = tid; q < 1024; q += 256) {
    float v = xs[q];
    mask[i * 1024 + q] = (v < thr) ? 0.f : ((v > thr) ? 1.f : v);
  }
}

// ---------------- final: out(B,C,H,W) = tmp(B,HW,C)^T + residual ----------------
__global__ __launch_bounds__(256) void out_kernel(const float* __restrict__ tmp,
                                                  const float* __restrict__ resid,
                                                  float* __restrict__ out) {
  int idx = blockIdx.x * 256 + threadIdx.x;
  if (idx >= 4 * CCH * 1024) return;
  int b = idx / (CCH * 1024);
  int rem = idx - b * CCH * 1024;
  int c = rem >> 10; int hw = rem & 1023;
  out[idx] = tmp[((size_t)b * 1024 + hw) * CCH + c] + resid[idx];
}

extern "C" void kernel_launch(void* const* d_in, const int* in_sizes, int n_in,
                              void* d_out, int out_size, void* d_ws, size_t ws_size,
                              hipStream_t stream) {
  auto F = [&](int i) { return (const float*)d_in[i]; };
  auto I = [&](int i) { return (const int*)d_in[i]; };

  float* ws = (float*)d_ws;
  float* h    = ws;                       // 1310720
  float* ffb  = h    + 1310720;           // 10485760 (ff intermediate, pout tmp)
  float* p2   = ffb  + 10485760;          // 2523136
  float* aph  = p2   + 2523136;           // 2048
  float* aeo  = aph  + 2048;              // 2048
  float* mask = aeo  + 2048;              // 2048

  // bf16 region
  unsigned short* b16   = (unsigned short*)(mask + 2048);
  unsigned short* lnb16 = b16;                 // 1310720
  unsigned short* attb16= lnb16 + 1310720;     // 1310720
  unsigned short* actb16= attb16 + 1310720;    // 5242880
  unsigned short* hb16  = actb16 + 5242880;    // 1310720
  unsigned short* enc16 = hb16 + 1310720;      // 236544
  unsigned short* qkv16 = enc16 + 236544;      // 3932160
  unsigned short* q16   = qkv16 + 3932160;     // 1310720 (q2, both blocks)
  unsigned short* kv16  = q16 + 1310720;       // 1310720 (kv, both blocks)
  unsigned short* wptr  = kv16 + 1310720;

  auto walloc = [&](int n) { unsigned short* p = wptr; wptr += n; return p; };
  unsigned short* pin_t  = walloc(102400);
  unsigned short* bqkv_t = walloc(307200);
  unsigned short* bow_t  = walloc(102400);
  unsigned short* bq2_t  = walloc(102400);
  unsigned short* bkv2_t = walloc(491520);
  unsigned short* bo2_t  = walloc(102400);
  unsigned short* bff1_t = walloc(819200);
  unsigned short* bff2_t = walloc(409600);
  unsigned short* iqkv_t = walloc(307200);
  unsigned short* iow_t  = walloc(102400);
  unsigned short* iq2_t  = walloc(102400);
  unsigned short* ikv2_t = walloc(204800);
  unsigned short* io2_t  = walloc(102400);
  unsigned short* iff1_t = walloc(819200);
  unsigned short* iff2_t = walloc(409600);
  unsigned short* pout_t = walloc(102400);

  float* ptmp = ffb;  // pout tmp (ffb dead by then)
  float* out = (float*)d_out;

  // --- weight conversion table ---
  WTab wt;
  int nt = 0, cnt = 0;
  auto addw = [&](const float* s, unsigned short* d, int K, int N) {
    wt.src[cnt] = s; wt.dst[cnt] = d; wt.Kd[cnt] = K; wt.Nd[cnt] = N; wt.tstart[cnt] = nt;
    nt += ((K + 31) / 32) * ((N + 31) / 32);
    cnt++;
  };
  addw(F(2), pin_t, 320, 320);
  addw(F(4 + 2), bqkv_t, 320, 960);
  addw(F(4 + 3), bow_t, 320, 320);
  addw(F(4 + 7), bq2_t, 320, 320);
  addw(F(4 + 8), bkv2_t, 768, 640);
  addw(F(4 + 9), bo2_t, 320, 320);
  addw(F(4 + 13), bff1_t, 320, 2560);
  addw(F(4 + 15), bff2_t, 1280, 320);
  addw(F(21 + 2), iqkv_t, 320, 960);
  addw(F(21 + 3), iow_t, 320, 320);
  addw(F(21 + 7), iq2_t, 320, 320);
  addw(F(21 + 8), ikv2_t, 320, 640);
  addw(F(21 + 9), io2_t, 320, 320);
  addw(F(21 + 13), iff1_t, 320, 2560);
  addw(F(21 + 15), iff2_t, 1280, 320);
  addw(F(38), pout_t, 320, 320);
  wt.tstart[16] = nt;

  wconv_kernel<<<nt, 256, 0, stream>>>(wt);
  conv_kernel<<<(236544 + 255) / 256, 256, 0, stream>>>(F(41), enc16, 236544);

  // N<=640 -> 64x64 tile (more blocks, less VGPR); else 128x128
  auto gemm = [&](const unsigned short* A, const unsigned short* Wt, const float* bias,
                  const float* res, void* o, int M, int N, int K, int obf) {
    if (N <= 640) {
      dim3 g((N + 63) / 64, (M + 63) / 64);
      mgemm64_kernel<<<g, 256, 0, stream>>>(A, Wt, bias, res, o, M, N, K, obf);
    } else {
      dim3 g((N + 127) / 128, (M + 127) / 128);
      mgemm_kernel<<<g, 256, 0, stream>>>(A, Wt, bias, res, o, M, N, K, obf);
    }
  };

  // GN + transpose -> lnb16 ; pin proj -> h (f32)
  gn_kernel<<<128, 256, 0, stream>>>(F(40), F(0), F(1), lnb16);
  gemm(lnb16, pin_t, F(3), nullptr, h, 4096, 320, 320, 0);

  auto run_block = [&](int p, int Bx, bool img_block,
                       const unsigned short* qkv_t, const unsigned short* ow_t,
                       const unsigned short* q2_t, const unsigned short* kv2_t,
                       const unsigned short* o2_t, const unsigned short* ff1_t,
                       const unsigned short* ff2_t) {
    int M = Bx * 1024;
    // ln1 -> qkv (bf16) -> mfma flash self-attn -> o-proj (+res)
    ln_kernel<<<M, 64, 0, stream>>>(h, F(p + 0), F(p + 1), lnb16, M);
    gemm(lnb16, qkv_t, nullptr, nullptr, qkv16, M, 960, 320, 1);
    mfattn_kernel<<<Bx * 128, 256, 0, stream>>>(qkv16, 960, qkv16 + 320, 960, qkv16 + 640, 960,
                                                nullptr, attb16, 320);
    gemm(attb16, ow_t, F(p + 4), h, h, M, 320, 320, 0);
    // ln2 -> cross-attn
    ln_kernel<<<M, 64, 0, stream>>>(h, F(p + 5), F(p + 6), lnb16, M);
    if (!img_block) {
      gemm(enc16, kv2_t, nullptr, nullptr, kv16, Bx * 77, 640, 768, 1);
      gemm(lnb16, q2_t, nullptr, nullptr, q16, M, 320, 320, 1);
      cattnm_kernel<<<Bx * 128, 256, 0, stream>>>(q16, kv16, attb16, p2);
    } else {
      conv_kernel<<<(655360 + 255) / 256, 256, 0, stream>>>(h + (size_t)2 * 1024 * 320, hb16, 655360);
      gemm(hb16, kv2_t, nullptr, nullptr, kv16, Bx * 1024, 640, 320, 1);
      gemm(lnb16, q2_t, nullptr, nullptr, q16, M, 320, 320, 1);
      mfattn_kernel<<<Bx * 128, 256, 0, stream>>>(q16, 320, kv16, 640, kv16 + 320, 640,
                                                  mask, attb16, 320);
    }
    gemm(attb16, o2_t, F(p + 10), h, h, M, 320, 320, 0);
    // ln3 -> ff
    ln_kernel<<<M, 64, 0, stream>>>(h, F(p + 11), F(p + 12), lnb16, M);
    gemm(lnb16, ff1_t, F(p + 14), nullptr, ffb, M, 2560, 320, 0);
    int ne = M * 1280;
    geglu_kernel<<<(ne + 255) / 256, 256, 0, stream>>>(ffb, actb16, M);
    gemm(actb16, ff2_t, F(p + 16), h, h, M, 320, 1280, 0);
  };

  // Block 1: all 4 batches, ctx = encoder_hidden_states, probs saved
  run_block(4, 4, false, bqkv_t, bow_t, bq2_t, bkv2_t, bo2_t, bff1_t, bff2_t);

  // attn_ph / attn_eot, loss, otsu mask
  extract_kernel<<<8, 256, 0, stream>>>(p2, I(42), I(43), I(44), I(45), aph, aeo);
  loss_kernel<<<1, 256, 0, stream>>>(aph, aeo, out + 1310720);
  otsu_kernel<<<2, 256, 0, stream>>>(aph, mask);

  // Block 2: batches 0-1 in place, ctx = batches 2-3 of h, bias = mask
  run_block(21, 2, true, iqkv_t, iow_t, iq2_t, ikv2_t, io2_t, iff1_t, iff2_t);

  // pout proj -> ptmp ; transpose + residual -> out
  conv_kernel<<<(1310720 + 255) / 256, 256, 0, stream>>>(h, hb16, 1310720);
  gemm(hb16, pout_t, F(39), nullptr, ptmp, 4096, 320, 320, 0);
  out_kernel<<<(1310720 + 255) / 256, 256, 0, stream>>>(ptmp, F(40), out);
}

// Round 8
// 704.984 us; speedup vs baseline: 1.0038x; 1.0038x over previous
//
#include <hip/hip_runtime.h>
#include <hip/hip_bf16.h>
#include <math.h>

#define NH 8
#define DH 40
#define CCH 320
#define SCALE 0.15811388300841897f

typedef __attribute__((ext_vector_type(8))) short short8;
typedef __attribute__((ext_vector_type(4))) float float4v;

static __device__ __forceinline__ unsigned short f2bf(float x) {
  __hip_bfloat16 t = __float2bfloat16(x);
  return *reinterpret_cast<unsigned short*>(&t);
}
static __device__ __forceinline__ float bf2f(unsigned short u) {
  return __uint_as_float(((unsigned)u) << 16);
}

// ---------------- GroupNorm (32 groups, eps 1e-6) + transpose to (B,HW,C), bf16 out ----------------
__global__ __launch_bounds__(256) void gn_kernel(const float* __restrict__ x,
                                                 const float* __restrict__ w,
                                                 const float* __restrict__ b,
                                                 unsigned short* __restrict__ out) {
  int batch = blockIdx.x >> 5;
  int g = blockIdx.x & 31;
  const int CPG = 10;
  const float* xp = x + ((size_t)batch * CCH + g * CPG) * 1024;
  float s = 0.f, ss = 0.f;
  for (int i = threadIdx.x; i < CPG * 1024; i += 256) { float v = xp[i]; s += v; ss += v * v; }
  __shared__ float r1[256], r2[256];
  r1[threadIdx.x] = s; r2[threadIdx.x] = ss; __syncthreads();
  for (int off = 128; off > 0; off >>= 1) {
    if (threadIdx.x < off) { r1[threadIdx.x] += r1[threadIdx.x + off]; r2[threadIdx.x] += r2[threadIdx.x + off]; }
    __syncthreads();
  }
  float mu = r1[0] * (1.f / 10240.f);
  float var = r2[0] * (1.f / 10240.f) - mu * mu;
  float inv = rsqrtf(var + 1e-6f);
  for (int i = threadIdx.x; i < CPG * 1024; i += 256) {
    int ci = i >> 10; int hw = i & 1023; int c = g * CPG + ci;
    float v = (xp[i] - mu) * inv * w[c] + b[c];
    out[((size_t)batch * 1024 + hw) * CCH + c] = f2bf(v);
  }
}

// ---------------- LayerNorm over C=320, eps 1e-5, one wave per row, bf16 out ----------------
__global__ __launch_bounds__(64) void ln_kernel(const float* __restrict__ x,
                                                const float* __restrict__ w,
                                                const float* __restrict__ b,
                                                unsigned short* __restrict__ out, int M) {
  int row = blockIdx.x;
  if (row >= M) return;
  const float* xp = x + (size_t)row * CCH;
  int lane = threadIdx.x;
  float v[5]; float s = 0.f;
#pragma unroll
  for (int i = 0; i < 5; i++) { v[i] = xp[lane + 64 * i]; s += v[i]; }
#pragma unroll
  for (int o = 32; o > 0; o >>= 1) s += __shfl_xor(s, o);
  float mu = s * (1.f / 320.f);
  float ss = 0.f;
#pragma unroll
  for (int i = 0; i < 5; i++) { float d = v[i] - mu; ss += d * d; }
#pragma unroll
  for (int o = 32; o > 0; o >>= 1) ss += __shfl_xor(ss, o);
  float inv = rsqrtf(ss * (1.f / 320.f) + 1e-5f);
  unsigned short* op = out + (size_t)row * CCH;
#pragma unroll
  for (int i = 0; i < 5; i++) { int c = lane + 64 * i; op[c] = f2bf((v[i] - mu) * inv * w[c] + b[c]); }
}

// ---------------- weight transpose+convert: W(KxN f32) -> Wt(NxK bf16) ----------------
struct WTab {
  const float* src[16];
  unsigned short* dst[16];
  int Kd[16];
  int Nd[16];
  int tstart[17];
};
__global__ __launch_bounds__(256) void wconv_kernel(WTab t) {
  __shared__ float tile[32][33];
  int gid = blockIdx.x;
  int w = 0;
  while (w < 15 && gid >= t.tstart[w + 1]) w++;
  int local = gid - t.tstart[w];
  int K = t.Kd[w], N = t.Nd[w];
  int ntx = (N + 31) >> 5;
  int bx = local % ntx, by = local / ntx;
  int nb = bx * 32, kb = by * 32;
  const float* src = t.src[w];
  unsigned short* dst = t.dst[w];
  int tx = threadIdx.x & 31, ty = threadIdx.x >> 5;
  for (int i = ty; i < 32; i += 8) {
    int k = kb + i, n = nb + tx;
    tile[i][tx] = (k < K && n < N) ? src[(size_t)k * N + n] : 0.f;
  }
  __syncthreads();
  for (int i = ty; i < 32; i += 8) {
    int n = nb + i, k = kb + tx;
    if (n < N && k < K) dst[(size_t)n * K + k] = f2bf(tile[tx][i]);
  }
}

// ---------------- f32 -> bf16 elementwise convert ----------------
__global__ __launch_bounds__(256) void conv_kernel(const float* __restrict__ src,
                                                   unsigned short* __restrict__ dst, int n) {
  int i = blockIdx.x * 256 + threadIdx.x;
  if (i < n) dst[i] = f2bf(src[i]);
}

// ---------------- bf16 MFMA GEMM 128x128 (BK=32): out = [res +] A @ Bt^T [+ bias] ----------------
__global__ __launch_bounds__(256) void mgemm_kernel(const unsigned short* __restrict__ A,
                                                    const unsigned short* __restrict__ Bt,
                                                    const float* __restrict__ bias,
                                                    const float* __restrict__ res,
                                                    void* __restrict__ outp,
                                                    int M, int N, int K, int obf) {
  __shared__ unsigned short As[128][40];
  __shared__ unsigned short Bs[128][40];
  int tid = threadIdx.x;
  int lane = tid & 63;
  int wave = tid >> 6;
  int wm = (wave & 1) * 64;
  int wn = (wave >> 1) * 64;
  int m0 = blockIdx.y * 128;
  int n0 = blockIdx.x * 128;
  float4v acc[4][4];
  float4v zero = {0.f, 0.f, 0.f, 0.f};
#pragma unroll
  for (int i = 0; i < 4; i++)
#pragma unroll
    for (int j = 0; j < 4; j++) acc[i][j] = zero;
  int r0 = tid >> 2;
  int kc = (tid & 3) * 8;
  short8 vzero = {0, 0, 0, 0, 0, 0, 0, 0};
  int fr = lane & 15;
  int kq = (lane >> 4) * 8;
  for (int k0 = 0; k0 < K; k0 += 32) {
#pragma unroll
    for (int i = 0; i < 2; i++) {
      int row = r0 + i * 64;
      int m = m0 + row;
      short8 av = vzero;
      if (m < M) av = *(const short8*)(A + (size_t)m * K + k0 + kc);
      *(short8*)&As[row][kc] = av;
      int n = n0 + row;
      short8 bv = vzero;
      if (n < N) bv = *(const short8*)(Bt + (size_t)n * K + k0 + kc);
      *(short8*)&Bs[row][kc] = bv;
    }
    __syncthreads();
    short8 af[4], bfr[4];
#pragma unroll
    for (int i = 0; i < 4; i++) af[i] = *(short8*)&As[wm + i * 16 + fr][kq];
#pragma unroll
    for (int j = 0; j < 4; j++) bfr[j] = *(short8*)&Bs[wn + j * 16 + fr][kq];
#pragma unroll
    for (int i = 0; i < 4; i++)
#pragma unroll
      for (int j = 0; j < 4; j++)
        acc[i][j] = __builtin_amdgcn_mfma_f32_16x16x32_bf16(af[i], bfr[j], acc[i][j], 0, 0, 0);
    __syncthreads();
  }
#pragma unroll
  for (int i = 0; i < 4; i++) {
    int mbase = m0 + wm + i * 16 + (lane >> 4) * 4;
#pragma unroll
    for (int j = 0; j < 4; j++) {
      int n = n0 + wn + j * 16 + (lane & 15);
      if (n >= N) continue;
      float bv = bias ? bias[n] : 0.f;
#pragma unroll
      for (int r = 0; r < 4; r++) {
        int m = mbase + r;
        if (m < M) {
          float v = acc[i][j][r] + bv;
          if (res) v += res[(size_t)m * N + n];
          if (obf) ((unsigned short*)outp)[(size_t)m * N + n] = f2bf(v);
          else ((float*)outp)[(size_t)m * N + n] = v;
        }
      }
    }
  }
}

// ---------------- bf16 MFMA GEMM 64x64, BK=160 (4 barriers for K=320) ----------------
__global__ __launch_bounds__(256) void mgemm64_kernel(const unsigned short* __restrict__ A,
                                                      const unsigned short* __restrict__ Bt,
                                                      const float* __restrict__ bias,
                                                      const float* __restrict__ res,
                                                      void* __restrict__ outp,
                                                      int M, int N, int K, int obf) {
  __shared__ unsigned short As[64][168];
  __shared__ unsigned short Bs[64][168];
  int tid = threadIdx.x;
  int lane = tid & 63;
  int wv = tid >> 6;
  int quad = lane >> 4;
  int col = lane & 15;
  int m0 = blockIdx.y * 64;
  int n0 = blockIdx.x * 64;
  float4v acc[4];
  float4v zero = {0.f, 0.f, 0.f, 0.f};
#pragma unroll
  for (int j = 0; j < 4; j++) acc[j] = zero;
  short8 vzero = {0, 0, 0, 0, 0, 0, 0, 0};
  for (int k0 = 0; k0 < K; k0 += 160) {
#pragma unroll
    for (int i = 0; i < 5; i++) {
      int u = tid + i * 256;            // 0..1279
      int row = u / 20, seg = u - row * 20;
      int k = k0 + seg * 8;
      int m = m0 + row;
      short8 av = vzero;
      if (m < M && k < K) av = *(const short8*)(A + (size_t)m * K + k);
      *(short8*)&As[row][seg * 8] = av;
      int n = n0 + row;
      short8 bv = vzero;
      if (n < N && k < K) bv = *(const short8*)(Bt + (size_t)n * K + k);
      *(short8*)&Bs[row][seg * 8] = bv;
    }
    __syncthreads();
#pragma unroll
    for (int kk = 0; kk < 5; kk++) {
      int kq2 = kk * 32 + quad * 8;
      short8 af = *(short8*)&As[wv * 16 + col][kq2];
#pragma unroll
      for (int j = 0; j < 4; j++) {
        short8 bfr = *(short8*)&Bs[j * 16 + col][kq2];
        acc[j] = __builtin_amdgcn_mfma_f32_16x16x32_bf16(af, bfr, acc[j], 0, 0, 0);
      }
    }
    __syncthreads();
  }
#pragma unroll
  for (int j = 0; j < 4; j++) {
    int n = n0 + j * 16 + col;
    if (n >= N) continue;
    float bv = bias ? bias[n] : 0.f;
#pragma unroll
    for (int r = 0; r < 4; r++) {
      int m = m0 + wv * 16 + quad * 4 + r;
      if (m < M) {
        float v = acc[j][r] + bv;
        if (res) v += res[(size_t)m * N + n];
        if (obf) ((unsigned short*)outp)[(size_t)m * N + n] = f2bf(v);
        else ((float*)outp)[(size_t)m * N + n] = v;
      }
    }
  }
}

// ---------------- split-K MFMA flash attention: 1024 keys, 4 splits of 256 ----------------
// grid: Bx*NH*16*4 blocks of 256 threads. Writes unnormalized O + m + l partials.
#define VSTR 72
__global__ __launch_bounds__(256) void mfattns_kernel(const unsigned short* __restrict__ qp, int qstr,
                                                      const unsigned short* __restrict__ kp, int kstr,
                                                      const unsigned short* __restrict__ vp, int vstr,
                                                      const float* __restrict__ bias,
                                                      float* __restrict__ Opart,
                                                      float* __restrict__ mpart,
                                                      float* __restrict__ lpart) {
  __shared__ unsigned short Ks[64 * 56];
  __shared__ unsigned short Vt[48 * VSTR];
  __shared__ unsigned short Ps[4][16 * 72];
  int tid = threadIdx.x;
  int lane = tid & 63;
  int wv = tid >> 6;
  int quad = lane >> 4;
  int col = lane & 15;
  int bid = blockIdx.x;
  int split = bid & 3;
  int qt = (bid >> 2) & 15;
  int h = (bid >> 6) & 7;
  int b = bid >> 9;

  short8 zero8 = {0, 0, 0, 0, 0, 0, 0, 0};
  int qrow = qt * 64 + wv * 16 + col;
  const unsigned short* qbase = qp + (size_t)(b * 1024 + qrow) * qstr + h * DH;
  short8 qf0 = *(const short8*)(qbase + quad * 8);
  short8 qf1 = (quad == 0) ? *(const short8*)(qbase + 32) : zero8;

  float4v Oacc[3];
  float4v fzero = {0.f, 0.f, 0.f, 0.f};
  Oacc[0] = fzero; Oacc[1] = fzero; Oacc[2] = fzero;
  float mr[4] = {-3.4e38f, -3.4e38f, -3.4e38f, -3.4e38f};
  float lr[4] = {0.f, 0.f, 0.f, 0.f};

  for (int kt = split * 4; kt < split * 4 + 4; kt++) {
    int kb = kt * 64;
    __syncthreads();
    for (int u = tid; u < 384; u += 256) {
      int key = u / 6, s = u - key * 6;
      short8 kv8 = zero8;
      if (s < 5) kv8 = *(const short8*)(kp + (size_t)(b * 1024 + kb + key) * kstr + h * DH + s * 8);
      *(short8*)&Ks[key * 56 + s * 8] = kv8;
    }
    for (int u = tid; u < 384; u += 256) {
      int s = u >> 6, key = u & 63;
      short8 vv8 = zero8;
      if (s < 5) vv8 = *(const short8*)(vp + (size_t)(b * 1024 + kb + key) * vstr + h * DH + s * 8);
#pragma unroll
      for (int j = 0; j < 8; j++) Vt[(s * 8 + j) * VSTR + key] = (unsigned short)vv8[j];
    }
    __syncthreads();

    float4v sf[4];
#pragma unroll
    for (int jb = 0; jb < 4; jb++) {
      const unsigned short* krow = &Ks[(jb * 16 + col) * 56];
      short8 bk0 = *(const short8*)(krow + quad * 8);
      short8 bk1 = (quad == 0) ? *(const short8*)(krow + 32) : zero8;
      float4v s = fzero;
      s = __builtin_amdgcn_mfma_f32_16x16x32_bf16(qf0, bk0, s, 0, 0, 0);
      s = __builtin_amdgcn_mfma_f32_16x16x32_bf16(qf1, bk1, s, 0, 0, 0);
      float bv = bias ? bias[b * 1024 + kb + jb * 16 + col] : 0.f;
#pragma unroll
      for (int r = 0; r < 4; r++) s[r] = s[r] * SCALE + bv;
      sf[jb] = s;
    }
    float tmax[4];
#pragma unroll
    for (int r = 0; r < 4; r++) {
      float t = fmaxf(fmaxf(sf[0][r], sf[1][r]), fmaxf(sf[2][r], sf[3][r]));
#pragma unroll
      for (int o = 1; o < 16; o <<= 1) t = fmaxf(t, __shfl_xor(t, o));
      tmax[r] = t;
    }
    float al[4];
#pragma unroll
    for (int r = 0; r < 4; r++) {
      float mnew = fmaxf(mr[r], tmax[r]);
      al[r] = __expf(mr[r] - mnew);
      mr[r] = mnew;
      lr[r] *= al[r];
    }
#pragma unroll
    for (int nb = 0; nb < 3; nb++)
#pragma unroll
      for (int r = 0; r < 4; r++) Oacc[nb][r] *= al[r];
    float rs[4] = {0.f, 0.f, 0.f, 0.f};
#pragma unroll
    for (int jb = 0; jb < 4; jb++) {
#pragma unroll
      for (int r = 0; r < 4; r++) {
        float p = __expf(sf[jb][r] - mr[r]);
        rs[r] += p;
        Ps[wv][(quad * 4 + r) * 72 + jb * 16 + col] = f2bf(p);
      }
    }
#pragma unroll
    for (int r = 0; r < 4; r++) {
      float t = rs[r];
#pragma unroll
      for (int o = 1; o < 16; o <<= 1) t += __shfl_xor(t, o);
      lr[r] += t;
    }
#pragma unroll
    for (int kc = 0; kc < 2; kc++) {
      int koff = kc * 32 + quad * 8;
      short8 pa = *(const short8*)&Ps[wv][col * 72 + koff];
#pragma unroll
      for (int nb = 0; nb < 3; nb++) {
        short8 vb = *(const short8*)&Vt[(nb * 16 + col) * VSTR + koff];
        Oacc[nb] = __builtin_amdgcn_mfma_f32_16x16x32_bf16(pa, vb, Oacc[nb], 0, 0, 0);
      }
    }
  }
  // write partials (unnormalized)
#pragma unroll
  for (int r = 0; r < 4; r++) {
    int qo = qt * 64 + wv * 16 + quad * 4 + r;
    size_t rowidx = (size_t)(b * NH + h) * 1024 + qo;
    float* orow = Opart + (rowidx * 4 + split) * DH;
#pragma unroll
    for (int nb = 0; nb < 3; nb++) {
      int d = nb * 16 + col;
      if (d < DH) orow[d] = Oacc[nb][r];
    }
    if (col == 0) {
      mpart[rowidx * 4 + split] = mr[r];
      lpart[rowidx * 4 + split] = lr[r];
    }
  }
}

// merge 4 split partials -> bf16 rows (attb16 layout, stride 320)
__global__ __launch_bounds__(256) void merge_kernel(const float* __restrict__ Opart,
                                                    const float* __restrict__ mpart,
                                                    const float* __restrict__ lpart,
                                                    unsigned short* __restrict__ op, int rows) {
  int r = blockIdx.x * 256 + threadIdx.x;
  if (r >= rows) return;
  float m0 = mpart[r * 4 + 0], m1 = mpart[r * 4 + 1], m2 = mpart[r * 4 + 2], m3 = mpart[r * 4 + 3];
  float M = fmaxf(fmaxf(m0, m1), fmaxf(m2, m3));
  float w0 = __expf(m0 - M), w1 = __expf(m1 - M), w2 = __expf(m2 - M), w3 = __expf(m3 - M);
  float L = lpart[r * 4 + 0] * w0 + lpart[r * 4 + 1] * w1 + lpart[r * 4 + 2] * w2 + lpart[r * 4 + 3] * w3;
  float inv = 1.f / L;
  w0 *= inv; w1 *= inv; w2 *= inv; w3 *= inv;
  int q = r & 1023;
  int h = (r >> 10) & 7;
  int b = r >> 13;
  const float4* p0 = (const float4*)(Opart + (size_t)(r * 4 + 0) * DH);
  const float4* p1 = (const float4*)(Opart + (size_t)(r * 4 + 1) * DH);
  const float4* p2 = (const float4*)(Opart + (size_t)(r * 4 + 2) * DH);
  const float4* p3 = (const float4*)(Opart + (size_t)(r * 4 + 3) * DH);
  unsigned short* o = op + ((size_t)(b * 1024 + q)) * 320 + h * DH;
#pragma unroll
  for (int j = 0; j < 10; j++) {
    float4 a = p0[j], bb = p1[j], c = p2[j], d = p3[j];
    ushort4 pk;
    pk.x = f2bf(a.x * w0 + bb.x * w1 + c.x * w2 + d.x * w3);
    pk.y = f2bf(a.y * w0 + bb.y * w1 + c.y * w2 + d.y * w3);
    pk.z = f2bf(a.z * w0 + bb.z * w1 + c.z * w2 + d.z * w3);
    pk.w = f2bf(a.w * w0 + bb.w * w1 + c.w * w2 + d.w * w3);
    *(ushort4*)(o + j * 4) = pk;
  }
}

// ---------------- MFMA cross-attention Lk=77 (bf16 in, bf16 out, f32 probs) ----------------
#define CVSTR 104
__global__ __launch_bounds__(256) void cattnm_kernel(const unsigned short* __restrict__ qp,
                                                     const unsigned short* __restrict__ kvp,
                                                     unsigned short* __restrict__ op,
                                                     float* __restrict__ probs) {
  __shared__ unsigned short Ks[80 * 56];
  __shared__ unsigned short Vt[48 * CVSTR];
  __shared__ unsigned short Ps[4][16 * 104];
  int tid = threadIdx.x;
  int lane = tid & 63;
  int wv = tid >> 6;
  int quad = lane >> 4;
  int col = lane & 15;
  int bid = blockIdx.x;
  int qt = bid & 15;
  int h = (bid >> 4) & 7;
  int b = bid >> 7;

  short8 zero8 = {0, 0, 0, 0, 0, 0, 0, 0};
  for (int u = tid; u < 480; u += 256) {
    int key = u / 6, s = u - key * 6;
    short8 v8 = zero8;
    if (s < 5 && key < 77) v8 = *(const short8*)(kvp + (size_t)(b * 77 + key) * 640 + h * DH + s * 8);
    *(short8*)&Ks[key * 56 + s * 8] = v8;
  }
  for (int u = tid; u < 576; u += 256) {
    int s = u / 96, key = u - s * 96;
    short8 v8 = zero8;
    if (s < 5 && key < 77) v8 = *(const short8*)(kvp + (size_t)(b * 77 + key) * 640 + 320 + h * DH + s * 8);
#pragma unroll
    for (int j = 0; j < 8; j++) Vt[(s * 8 + j) * CVSTR + key] = (unsigned short)v8[j];
  }
  int qrow = qt * 64 + wv * 16 + col;
  const unsigned short* qbase = qp + (size_t)(b * 1024 + qrow) * CCH + h * DH;
  short8 qf0 = *(const short8*)(qbase + quad * 8);
  short8 qf1 = (quad == 0) ? *(const short8*)(qbase + 32) : zero8;
  __syncthreads();

  float4v fzero = {0.f, 0.f, 0.f, 0.f};
  float4v sf[5];
#pragma unroll
  for (int jb = 0; jb < 5; jb++) {
    const unsigned short* krow = &Ks[(jb * 16 + col) * 56];
    short8 bk0 = *(const short8*)(krow + quad * 8);
    short8 bk1 = (quad == 0) ? *(const short8*)(krow + 32) : zero8;
    float4v s = fzero;
    s = __builtin_amdgcn_mfma_f32_16x16x32_bf16(qf0, bk0, s, 0, 0, 0);
    s = __builtin_amdgcn_mfma_f32_16x16x32_bf16(qf1, bk1, s, 0, 0, 0);
    int key = jb * 16 + col;
    float msk = (key < 77) ? 0.f : -3.4e38f;
#pragma unroll
    for (int r = 0; r < 4; r++) s[r] = s[r] * SCALE + msk;
    sf[jb] = s;
  }
  float inv[4];
#pragma unroll
  for (int r = 0; r < 4; r++) {
    float t = sf[0][r];
#pragma unroll
    for (int jb = 1; jb < 5; jb++) t = fmaxf(t, sf[jb][r]);
#pragma unroll
    for (int o = 1; o < 16; o <<= 1) t = fmaxf(t, __shfl_xor(t, o));
    float sum = 0.f;
#pragma unroll
    for (int jb = 0; jb < 5; jb++) { float e = __expf(sf[jb][r] - t); sf[jb][r] = e; sum += e; }
#pragma unroll
    for (int o = 1; o < 16; o <<= 1) sum += __shfl_xor(sum, o);
    inv[r] = 1.f / sum;
  }
#pragma unroll
  for (int jb = 0; jb < 5; jb++) {
    int key = jb * 16 + col;
#pragma unroll
    for (int r = 0; r < 4; r++) {
      float p = sf[jb][r] * inv[r];
      Ps[wv][(quad * 4 + r) * 104 + jb * 16 + col] = f2bf(p);
      if (key < 77) {
        int row = qt * 64 + wv * 16 + quad * 4 + r;
        probs[((size_t)(b * NH + h) * 1024 + row) * 77 + key] = p;
      }
    }
  }
  float4v Oacc[3];
  Oacc[0] = fzero; Oacc[1] = fzero; Oacc[2] = fzero;
#pragma unroll
  for (int kc = 0; kc < 3; kc++) {
    int koff = kc * 32 + quad * 8;
    short8 pa = (koff < 80) ? *(const short8*)&Ps[wv][col * 104 + koff] : zero8;
#pragma unroll
    for (int nb = 0; nb < 3; nb++) {
      short8 vb = *(const short8*)&Vt[(nb * 16 + col) * CVSTR + koff];
      Oacc[nb] = __builtin_amdgcn_mfma_f32_16x16x32_bf16(pa, vb, Oacc[nb], 0, 0, 0);
    }
  }
#pragma unroll
  for (int r = 0; r < 4; r++) {
    int qo = qt * 64 + wv * 16 + quad * 4 + r;
    unsigned short* orow = op + (size_t)(b * 1024 + qo) * CCH + h * DH;
#pragma unroll
    for (int nb = 0; nb < 3; nb++) {
      int d = nb * 16 + col;
      if (d < DH) orow[d] = f2bf(Oacc[nb][r]);
    }
  }
}

// ---------------- geglu (bf16 in, bf16 out, x4 vectorized) ----------------
__global__ __launch_bounds__(256) void geglu_kernel(const unsigned short* __restrict__ ff,
                                                    unsigned short* __restrict__ act, int M) {
  int idx = blockIdx.x * 256 + threadIdx.x;
  if (idx >= M * 320) return;
  int m = idx / 320; int j4 = (idx - m * 320) * 4;
  ushort4 a4 = *(const ushort4*)&ff[(size_t)m * 2560 + j4];
  ushort4 g4 = *(const ushort4*)&ff[(size_t)m * 2560 + 1280 + j4];
  ushort4 o4;
  {
    float a = bf2f(a4.x), g = bf2f(g4.x);
    float t = tanhf(0.7978845608028654f * (g + 0.044715f * g * g * g));
    o4.x = f2bf(a * (0.5f * g * (1.f + t)));
  }
  {
    float a = bf2f(a4.y), g = bf2f(g4.y);
    float t = tanhf(0.7978845608028654f * (g + 0.044715f * g * g * g));
    o4.y = f2bf(a * (0.5f * g * (1.f + t)));
  }
  {
    float a = bf2f(a4.z), g = bf2f(g4.z);
    float t = tanhf(0.7978845608028654f * (g + 0.044715f * g * g * g));
    o4.z = f2bf(a * (0.5f * g * (1.f + t)));
  }
  {
    float a = bf2f(a4.w), g = bf2f(g4.w);
    float t = tanhf(0.7978845608028654f * (g + 0.044715f * g * g * g));
    o4.w = f2bf(a * (0.5f * g * (1.f + t)));
  }
  *(ushort4*)&act[(size_t)m * 1280 + j4] = o4;
}

// ---------------- extract attn_ph / attn_eot from p2 (B,8,1024,77) ----------------
__global__ __launch_bounds__(256) void extract_kernel(const float* __restrict__ p2,
                                                      const int* __restrict__ phb, const int* __restrict__ pht,
                                                      const int* __restrict__ eob, const int* __restrict__ eot,
                                                      float* __restrict__ aph, float* __restrict__ aeo) {
  int idx = blockIdx.x * 256 + threadIdx.x;
  if (idx >= 2048) return;
  int i = idx >> 10, q = idx & 1023;
  int pb = phb[i], pt = pht[i], eb = eob[i], et = eot[i];
  float s1 = 0.f, s2 = 0.f;
#pragma unroll
  for (int hh = 0; hh < NH; hh++) {
    s1 += p2[(((size_t)(2 + pb) * NH + hh) * 1024 + q) * 77 + pt];
    s2 += p2[(((size_t)(2 + eb) * NH + hh) * 1024 + q) * 77 + et];
  }
  aph[idx] = s1 * 0.125f;
  aeo[idx] = s2 * 0.125f;
}

// ---------------- loss_reg ----------------
__global__ __launch_bounds__(256) void loss_kernel(const float* __restrict__ ph,
                                                   const float* __restrict__ eo,
                                                   float* __restrict__ out) {
  __shared__ float red[256];
  int tid = threadIdx.x;
  float total = 0.f;
  for (int i = 0; i < 2; i++) {
    float mp = -3.4e38f, me = -3.4e38f;
    for (int q = tid; q < 1024; q += 256) { mp = fmaxf(mp, ph[i * 1024 + q]); me = fmaxf(me, eo[i * 1024 + q]); }
    red[tid] = mp; __syncthreads();
    for (int o = 128; o > 0; o >>= 1) { if (tid < o) red[tid] = fmaxf(red[tid], red[tid + o]); __syncthreads(); }
    mp = red[0]; __syncthreads();
    red[tid] = me; __syncthreads();
    for (int o = 128; o > 0; o >>= 1) { if (tid < o) red[tid] = fmaxf(red[tid], red[tid + o]); __syncthreads(); }
    me = red[0]; __syncthreads();
    float part = 0.f;
    for (int q = tid; q < 1024; q += 256) {
      float d = ph[i * 1024 + q] / mp - eo[i * 1024 + q] / me;
      part += d * d;
    }
    red[tid] = part; __syncthreads();
    for (int o = 128; o > 0; o >>= 1) { if (tid < o) red[tid] += red[tid + o]; __syncthreads(); }
    total += red[0]; __syncthreads();
  }
  if (tid == 0) out[0] = total * (1.f / 2048.f);
}

// ---------------- otsu per row of 1024 ----------------
__global__ __launch_bounds__(256) void otsu_kernel(const float* __restrict__ mrow,
                                                   float* __restrict__ mask) {
  __shared__ float xs[1024];
  __shared__ float red[256];
  __shared__ float cl[10], sl[10];
  __shared__ float shthr;
  int i = blockIdx.x, tid = threadIdx.x;
  const float* mp = mrow + i * 1024;
  for (int q = tid; q < 1024; q += 256) xs[q] = mp[q];
  __syncthreads();
  float mn = 3.4e38f, mx = -3.4e38f;
  for (int q = tid; q < 1024; q += 256) { mn = fminf(mn, xs[q]); mx = fmaxf(mx, xs[q]); }
  red[tid] = mn; __syncthreads();
  for (int o = 128; o > 0; o >>= 1) { if (tid < o) red[tid] = fminf(red[tid], red[tid + o]); __syncthreads(); }
  mn = red[0]; __syncthreads();
  red[tid] = mx; __syncthreads();
  for (int o = 128; o > 0; o >>= 1) { if (tid < o) red[tid] = fmaxf(red[tid], red[tid + o]); __syncthreads(); }
  mx = red[0]; __syncthreads();
  float inv = 1.f / (mx - mn);
  for (int q = tid; q < 1024; q += 256) xs[q] = (xs[q] - mn) * inv;
  __syncthreads();
  float t0 = 0.f;
  for (int q = tid; q < 1024; q += 256) t0 += xs[q];
  red[tid] = t0; __syncthreads();
  for (int o = 128; o > 0; o >>= 1) { if (tid < o) red[tid] += red[tid + o]; __syncthreads(); }
  float total = red[0]; __syncthreads();
  for (int t = 0; t < 10; t++) {
    float th = t * 0.1f;
    float c = 0.f, s = 0.f;
    for (int q = tid; q < 1024; q += 256) { float v = xs[q]; if (v < th) { c += 1.f; s += v; } }
    red[tid] = c; __syncthreads();
    for (int o = 128; o > 0; o >>= 1) { if (tid < o) red[tid] += red[tid + o]; __syncthreads(); }
    if (tid == 0) cl[t] = red[0];
    __syncthreads();
    red[tid] = s; __syncthreads();
    for (int o = 128; o > 0; o >>= 1) { if (tid < o) red[tid] += red[tid + o]; __syncthreads(); }
    if (tid == 0) sl[t] = red[0];
    __syncthreads();
  }
  if (tid == 0) {
    float gmax = -3.4e38f; int best = 0;
    for (int t = 0; t < 10; t++) {
      float c_low = cl[t], c_high = 1024.f - c_low;
      float g;
      if (c_low > 0.f && c_high > 0.f) {
        float mu_l = sl[t] / c_low;
        float mu_h = (total - sl[t]) / c_high;
        float d = mu_l - mu_h;
        g = (c_low * (1.f / 1024.f)) * (c_high * (1.f / 1024.f)) * d * d;
      } else g = -3.4e38f;
      if (g > gmax) { gmax = g; best = t; }
    }
    shthr = (gmax > 0.f) ? best * 0.1f : 0.f;
  }
  __syncthreads();
  float thr = shthr;
  for (int q = tid; q < 1024; q += 256) {
    float v = xs[q];
    mask[i * 1024 + q] = (v < thr) ? 0.f : ((v > thr) ? 1.f : v);
  }
}

// ---------------- final: out(B,C,H,W) = tmp(B,HW,C)^T + residual ----------------
__global__ __launch_bounds__(256) void out_kernel(const float* __restrict__ tmp,
                                                  const float* __restrict__ resid,
                                                  float* __restrict__ out) {
  int idx = blockIdx.x * 256 + threadIdx.x;
  if (idx >= 4 * CCH * 1024) return;
  int b = idx / (CCH * 1024);
  int rem = idx - b * CCH * 1024;
  int c = rem >> 10; int hw = rem & 1023;
  out[idx] = tmp[((size_t)b * 1024 + hw) * CCH + c] + resid[idx];
}

extern "C" void kernel_launch(void* const* d_in, const int* in_sizes, int n_in,
                              void* d_out, int out_size, void* d_ws, size_t ws_size,
                              hipStream_t stream) {
  auto F = [&](int i) { return (const float*)d_in[i]; };
  auto I = [&](int i) { return (const int*)d_in[i]; };

  float* ws = (float*)d_ws;
  float* h    = ws;                       // 1310720
  float* ffb  = h    + 1310720;           // 10485760 f32 region: attn partials, bf16 ff intermediate, pout tmp
  float* p2   = ffb  + 10485760;          // 2523136
  float* aph  = p2   + 2523136;           // 2048
  float* aeo  = aph  + 2048;              // 2048
  float* mask = aeo  + 2048;              // 2048

  // attention split partials (inside ffb; dead when ff uses it)
  float* Opart = ffb;                       // 32768*4*40 = 5242880
  float* mpart = ffb + 5242880;             // 131072
  float* lpart = ffb + 5242880 + 131072;    // 131072
  unsigned short* ffb16 = (unsigned short*)ffb;  // ff intermediate (M*2560 bf16)
  float* ptmp = ffb;                        // pout tmp

  // bf16 region
  unsigned short* b16   = (unsigned short*)(mask + 2048);
  unsigned short* lnb16 = b16;                 // 1310720
  unsigned short* attb16= lnb16 + 1310720;     // 1310720
  unsigned short* actb16= attb16 + 1310720;    // 5242880
  unsigned short* hb16  = actb16 + 5242880;    // 1310720
  unsigned short* enc16 = hb16 + 1310720;      // 236544
  unsigned short* qkv16 = enc16 + 236544;      // 3932160
  unsigned short* q16   = qkv16 + 3932160;     // 1310720
  unsigned short* kv16  = q16 + 1310720;       // 1310720
  unsigned short* wptr  = kv16 + 1310720;

  auto walloc = [&](int n) { unsigned short* p = wptr; wptr += n; return p; };
  unsigned short* pin_t  = walloc(102400);
  unsigned short* bqkv_t = walloc(307200);
  unsigned short* bow_t  = walloc(102400);
  unsigned short* bq2_t  = walloc(102400);
  unsigned short* bkv2_t = walloc(491520);
  unsigned short* bo2_t  = walloc(102400);
  unsigned short* bff1_t = walloc(819200);
  unsigned short* bff2_t = walloc(409600);
  unsigned short* iqkv_t = walloc(307200);
  unsigned short* iow_t  = walloc(102400);
  unsigned short* iq2_t  = walloc(102400);
  unsigned short* ikv2_t = walloc(204800);
  unsigned short* io2_t  = walloc(102400);
  unsigned short* iff1_t = walloc(819200);
  unsigned short* iff2_t = walloc(409600);
  unsigned short* pout_t = walloc(102400);

  float* out = (float*)d_out;

  // --- weight conversion table ---
  WTab wt;
  int nt = 0, cnt = 0;
  auto addw = [&](const float* s, unsigned short* d, int K, int N) {
    wt.src[cnt] = s; wt.dst[cnt] = d; wt.Kd[cnt] = K; wt.Nd[cnt] = N; wt.tstart[cnt] = nt;
    nt += ((K + 31) / 32) * ((N + 31) / 32);
    cnt++;
  };
  addw(F(2), pin_t, 320, 320);
  addw(F(4 + 2), bqkv_t, 320, 960);
  addw(F(4 + 3), bow_t, 320, 320);
  addw(F(4 + 7), bq2_t, 320, 320);
  addw(F(4 + 8), bkv2_t, 768, 640);
  addw(F(4 + 9), bo2_t, 320, 320);
  addw(F(4 + 13), bff1_t, 320, 2560);
  addw(F(4 + 15), bff2_t, 1280, 320);
  addw(F(21 + 2), iqkv_t, 320, 960);
  addw(F(21 + 3), iow_t, 320, 320);
  addw(F(21 + 7), iq2_t, 320, 320);
  addw(F(21 + 8), ikv2_t, 320, 640);
  addw(F(21 + 9), io2_t, 320, 320);
  addw(F(21 + 13), iff1_t, 320, 2560);
  addw(F(21 + 15), iff2_t, 1280, 320);
  addw(F(38), pout_t, 320, 320);
  wt.tstart[16] = nt;

  wconv_kernel<<<nt, 256, 0, stream>>>(wt);
  conv_kernel<<<(236544 + 255) / 256, 256, 0, stream>>>(F(41), enc16, 236544);

  auto gemm = [&](const unsigned short* A, const unsigned short* Wt, const float* bias,
                  const float* res, void* o, int M, int N, int K, int obf) {
    if (N <= 640) {
      dim3 g((N + 63) / 64, (M + 63) / 64);
      mgemm64_kernel<<<g, 256, 0, stream>>>(A, Wt, bias, res, o, M, N, K, obf);
    } else {
      dim3 g((N + 127) / 128, (M + 127) / 128);
      mgemm_kernel<<<g, 256, 0, stream>>>(A, Wt, bias, res, o, M, N, K, obf);
    }
  };

  // GN + transpose -> lnb16 ; pin proj -> h (f32)
  gn_kernel<<<128, 256, 0, stream>>>(F(40), F(0), F(1), lnb16);
  gemm(lnb16, pin_t, F(3), nullptr, h, 4096, 320, 320, 0);

  auto run_block = [&](int p, int Bx, bool img_block,
                       const unsigned short* qkv_t, const unsigned short* ow_t,
                       const unsigned short* q2_t, const unsigned short* kv2_t,
                       const unsigned short* o2_t, const unsigned short* ff1_t,
                       const unsigned short* ff2_t) {
    int M = Bx * 1024;
    // ln1 -> qkv (bf16) -> split-K mfma flash self-attn -> merge -> o-proj (+res)
    ln_kernel<<<M, 64, 0, stream>>>(h, F(p + 0), F(p + 1), lnb16, M);
    gemm(lnb16, qkv_t, nullptr, nullptr, qkv16, M, 960, 320, 1);
    mfattns_kernel<<<Bx * 512, 256, 0, stream>>>(qkv16, 960, qkv16 + 320, 960, qkv16 + 640, 960,
                                                 nullptr, Opart, mpart, lpart);
    merge_kernel<<<Bx * 32, 256, 0, stream>>>(Opart, mpart, lpart, attb16, Bx * 8192);
    gemm(attb16, ow_t, F(p + 4), h, h, M, 320, 320, 0);
    // ln2 -> cross-attn
    ln_kernel<<<M, 64, 0, stream>>>(h, F(p + 5), F(p + 6), lnb16, M);
    if (!img_block) {
      gemm(enc16, kv2_t, nullptr, nullptr, kv16, Bx * 77, 640, 768, 1);
      gemm(lnb16, q2_t, nullptr, nullptr, q16, M, 320, 320, 1);
      cattnm_kernel<<<Bx * 128, 256, 0, stream>>>(q16, kv16, attb16, p2);
    } else {
      conv_kernel<<<(655360 + 255) / 256, 256, 0, stream>>>(h + (size_t)2 * 1024 * 320, hb16, 655360);
      gemm(hb16, kv2_t, nullptr, nullptr, kv16, Bx * 1024, 640, 320, 1);
      gemm(lnb16, q2_t, nullptr, nullptr, q16, M, 320, 320, 1);
      mfattns_kernel<<<Bx * 512, 256, 0, stream>>>(q16, 320, kv16, 640, kv16 + 320, 640,
                                                   mask, Opart, mpart, lpart);
      merge_kernel<<<Bx * 32, 256, 0, stream>>>(Opart, mpart, lpart, attb16, Bx * 8192);
    }
    gemm(attb16, o2_t, F(p + 10), h, h, M, 320, 320, 0);
    // ln3 -> ff (bf16 intermediate)
    ln_kernel<<<M, 64, 0, stream>>>(h, F(p + 11), F(p + 12), lnb16, M);
    gemm(lnb16, ff1_t, F(p + 14), nullptr, ffb16, M, 2560, 320, 1);
    int ne = M * 320;
    geglu_kernel<<<(ne + 255) / 256, 256, 0, stream>>>(ffb16, actb16, M);
    gemm(actb16, ff2_t, F(p + 16), h, h, M, 320, 1280, 0);
  };

  // Block 1: all 4 batches, ctx = encoder_hidden_states, probs saved
  run_block(4, 4, false, bqkv_t, bow_t, bq2_t, bkv2_t, bo2_t, bff1_t, bff2_t);

  // attn_ph / attn_eot, loss, otsu mask
  extract_kernel<<<8, 256, 0, stream>>>(p2, I(42), I(43), I(44), I(45), aph, aeo);
  loss_kernel<<<1, 256, 0, stream>>>(aph, aeo, out + 1310720);
  otsu_kernel<<<2, 256, 0, stream>>>(aph, mask);

  // Block 2: batches 0-1 in place, ctx = batches 2-3 of h, bias = mask
  run_block(21, 2, true, iqkv_t, iow_t, iq2_t, ikv2_t, io2_t, iff1_t, iff2_t);

  // pout proj -> ptmp ; transpose + residual -> out
  conv_kernel<<<(1310720 + 255) / 256, 256, 0, stream>>>(h, hb16, 1310720);
  gemm(hb16, pout_t, F(39), nullptr, ptmp, 4096, 320, 320, 0);
  out_kernel<<<(1310720 + 255) / 256, 256, 0, stream>>>(ptmp, F(40), out);
}

// Round 9
// 677.495 us; speedup vs baseline: 1.0445x; 1.0406x over previous
//
#include <hip/hip_runtime.h>
#include <hip/hip_bf16.h>
#include <math.h>

#define NH 8
#define DH 40
#define CCH 320
#define SCALE 0.15811388300841897f

typedef __attribute__((ext_vector_type(8))) short short8;
typedef __attribute__((ext_vector_type(4))) float float4v;

static __device__ __forceinline__ unsigned short f2bf(float x) {
  __hip_bfloat16 t = __float2bfloat16(x);
  return *reinterpret_cast<unsigned short*>(&t);
}
static __device__ __forceinline__ float bf2f(unsigned short u) {
  return __uint_as_float(((unsigned)u) << 16);
}

// ---------------- GroupNorm (32 groups, eps 1e-6) + transpose to (B,HW,C), bf16 out ----------------
__global__ __launch_bounds__(256) void gn_kernel(const float* __restrict__ x,
                                                 const float* __restrict__ w,
                                                 const float* __restrict__ b,
                                                 unsigned short* __restrict__ out) {
  int batch = blockIdx.x >> 5;
  int g = blockIdx.x & 31;
  const int CPG = 10;
  const float* xp = x + ((size_t)batch * CCH + g * CPG) * 1024;
  float s = 0.f, ss = 0.f;
  for (int i = threadIdx.x; i < CPG * 1024; i += 256) { float v = xp[i]; s += v; ss += v * v; }
  __shared__ float r1[256], r2[256];
  r1[threadIdx.x] = s; r2[threadIdx.x] = ss; __syncthreads();
  for (int off = 128; off > 0; off >>= 1) {
    if (threadIdx.x < off) { r1[threadIdx.x] += r1[threadIdx.x + off]; r2[threadIdx.x] += r2[threadIdx.x + off]; }
    __syncthreads();
  }
  float mu = r1[0] * (1.f / 10240.f);
  float var = r2[0] * (1.f / 10240.f) - mu * mu;
  float inv = rsqrtf(var + 1e-6f);
  for (int i = threadIdx.x; i < CPG * 1024; i += 256) {
    int ci = i >> 10; int hw = i & 1023; int c = g * CPG + ci;
    float v = (xp[i] - mu) * inv * w[c] + b[c];
    out[((size_t)batch * 1024 + hw) * CCH + c] = f2bf(v);
  }
}

// ---------------- LayerNorm over C=320, eps 1e-5, one wave per row, bf16 out ----------------
__global__ __launch_bounds__(64) void ln_kernel(const float* __restrict__ x,
                                                const float* __restrict__ w,
                                                const float* __restrict__ b,
                                                unsigned short* __restrict__ out, int M) {
  int row = blockIdx.x;
  if (row >= M) return;
  const float* xp = x + (size_t)row * CCH;
  int lane = threadIdx.x;
  float v[5]; float s = 0.f;
#pragma unroll
  for (int i = 0; i < 5; i++) { v[i] = xp[lane + 64 * i]; s += v[i]; }
#pragma unroll
  for (int o = 32; o > 0; o >>= 1) s += __shfl_xor(s, o);
  float mu = s * (1.f / 320.f);
  float ss = 0.f;
#pragma unroll
  for (int i = 0; i < 5; i++) { float d = v[i] - mu; ss += d * d; }
#pragma unroll
  for (int o = 32; o > 0; o >>= 1) ss += __shfl_xor(ss, o);
  float inv = rsqrtf(ss * (1.f / 320.f) + 1e-5f);
  unsigned short* op = out + (size_t)row * CCH;
#pragma unroll
  for (int i = 0; i < 5; i++) { int c = lane + 64 * i; op[c] = f2bf((v[i] - mu) * inv * w[c] + b[c]); }
}

// ---------------- weight transpose+convert: W(KxN f32) -> Wt(NxK bf16) ----------------
// perm=1 (ff1): output column remap so each 64-wide tile holds [a(32) | g(32)] pairs.
struct WTab {
  const float* src[16];
  unsigned short* dst[16];
  int Kd[16];
  int Nd[16];
  int perm[16];
  int tstart[17];
  float* lz;   // loss accumulator to zero
};
__global__ __launch_bounds__(256) void wconv_kernel(WTab t) {
  __shared__ float tile[32][33];
  if (blockIdx.x == 0 && threadIdx.x == 0) *t.lz = 0.f;
  int gid = blockIdx.x;
  int w = 0;
  while (w < 15 && gid >= t.tstart[w + 1]) w++;
  int local = gid - t.tstart[w];
  int K = t.Kd[w], N = t.Nd[w];
  int ntx = (N + 31) >> 5;
  int bx = local % ntx, by = local / ntx;
  int nb = bx * 32, kb = by * 32;
  const float* src = t.src[w];
  unsigned short* dst = t.dst[w];
  int doperm = t.perm[w];
  int half = N >> 1;
  int tx = threadIdx.x & 31, ty = threadIdx.x >> 5;
  for (int i = ty; i < 32; i += 8) {
    int k = kb + i, n = nb + tx;
    tile[i][tx] = (k < K && n < N) ? src[(size_t)k * N + n] : 0.f;
  }
  __syncthreads();
  for (int i = ty; i < 32; i += 8) {
    int n = nb + i, k = kb + tx;
    if (n < N && k < K) {
      int nd = n;
      if (doperm) {
        if (n < half) nd = (n >> 5) * 64 + (n & 31);
        else { int c = n - half; nd = (c >> 5) * 64 + 32 + (c & 31); }
      }
      dst[(size_t)nd * K + k] = f2bf(tile[tx][i]);
    }
  }
}

// ---------------- bf16 MFMA GEMM 128x128 (BK=32); gl=1: fused GEGLU epilogue ----------------
__global__ __launch_bounds__(256) void mgemm_kernel(const unsigned short* __restrict__ A,
                                                    const unsigned short* __restrict__ Bt,
                                                    const float* __restrict__ bias,
                                                    const float* __restrict__ res,
                                                    void* __restrict__ outp,
                                                    int M, int N, int K, int obf, int gl) {
  __shared__ unsigned short As[128][40];
  __shared__ unsigned short Bs[128][40];
  int tid = threadIdx.x;
  int lane = tid & 63;
  int wave = tid >> 6;
  int wm = (wave & 1) * 64;
  int wn = (wave >> 1) * 64;
  int m0 = blockIdx.y * 128;
  int n0 = blockIdx.x * 128;
  float4v acc[4][4];
  float4v zero = {0.f, 0.f, 0.f, 0.f};
#pragma unroll
  for (int i = 0; i < 4; i++)
#pragma unroll
    for (int j = 0; j < 4; j++) acc[i][j] = zero;
  int r0 = tid >> 2;
  int kc = (tid & 3) * 8;
  short8 vzero = {0, 0, 0, 0, 0, 0, 0, 0};
  int fr = lane & 15;
  int kq = (lane >> 4) * 8;
  for (int k0 = 0; k0 < K; k0 += 32) {
#pragma unroll
    for (int i = 0; i < 2; i++) {
      int row = r0 + i * 64;
      int m = m0 + row;
      short8 av = vzero;
      if (m < M) av = *(const short8*)(A + (size_t)m * K + k0 + kc);
      *(short8*)&As[row][kc] = av;
      int n = n0 + row;
      short8 bv = vzero;
      if (n < N) bv = *(const short8*)(Bt + (size_t)n * K + k0 + kc);
      *(short8*)&Bs[row][kc] = bv;
    }
    __syncthreads();
    short8 af[4], bfr[4];
#pragma unroll
    for (int i = 0; i < 4; i++) af[i] = *(short8*)&As[wm + i * 16 + fr][kq];
#pragma unroll
    for (int j = 0; j < 4; j++) bfr[j] = *(short8*)&Bs[wn + j * 16 + fr][kq];
#pragma unroll
    for (int i = 0; i < 4; i++)
#pragma unroll
      for (int j = 0; j < 4; j++)
        acc[i][j] = __builtin_amdgcn_mfma_f32_16x16x32_bf16(af[i], bfr[j], acc[i][j], 0, 0, 0);
    __syncthreads();
  }
  if (gl) {
    // GEGLU: cols [0,32) of this wave-tile are 'a', [32,64) are 'g' (same thread: j and j+2).
    int half = N >> 1;
#pragma unroll
    for (int i = 0; i < 4; i++) {
      int mbase = m0 + wm + i * 16 + (lane >> 4) * 4;
#pragma unroll
      for (int jb = 0; jb < 2; jb++) {
        int nout = ((n0 + wn) >> 1) + jb * 16 + (lane & 15);
        float ba = bias[nout];
        float bg = bias[half + nout];
#pragma unroll
        for (int r = 0; r < 4; r++) {
          int m = mbase + r;
          if (m < M) {
            float a = acc[i][jb][r] + ba;
            float g = acc[i][jb + 2][r] + bg;
            float t = tanhf(0.7978845608028654f * (g + 0.044715f * g * g * g));
            ((unsigned short*)outp)[(size_t)m * half + nout] = f2bf(a * (0.5f * g * (1.f + t)));
          }
        }
      }
    }
    return;
  }
#pragma unroll
  for (int i = 0; i < 4; i++) {
    int mbase = m0 + wm + i * 16 + (lane >> 4) * 4;
#pragma unroll
    for (int j = 0; j < 4; j++) {
      int n = n0 + wn + j * 16 + (lane & 15);
      if (n >= N) continue;
      float bv = bias ? bias[n] : 0.f;
#pragma unroll
      for (int r = 0; r < 4; r++) {
        int m = mbase + r;
        if (m < M) {
          float v = acc[i][j][r] + bv;
          if (res) v += res[(size_t)m * N + n];
          if (obf) ((unsigned short*)outp)[(size_t)m * N + n] = f2bf(v);
          else ((float*)outp)[(size_t)m * N + n] = v;
        }
      }
    }
  }
}

// ---------------- bf16 MFMA GEMM 64x64, BK=160; a32: f32 A staging; omode 0=f32,1=bf16,2=transpose+residual ----------------
__global__ __launch_bounds__(256) void mgemm64_kernel(const void* __restrict__ Ap,
                                                      const unsigned short* __restrict__ Bt,
                                                      const float* __restrict__ bias,
                                                      const float* __restrict__ res,
                                                      void* __restrict__ outp,
                                                      int M, int N, int K, int a32, int omode) {
  __shared__ unsigned short As[64][168];
  __shared__ unsigned short Bs[64][168];
  int tid = threadIdx.x;
  int lane = tid & 63;
  int wv = tid >> 6;
  int quad = lane >> 4;
  int col = lane & 15;
  int m0 = blockIdx.y * 64;
  int n0 = blockIdx.x * 64;
  float4v acc[4];
  float4v zero = {0.f, 0.f, 0.f, 0.f};
#pragma unroll
  for (int j = 0; j < 4; j++) acc[j] = zero;
  short8 vzero = {0, 0, 0, 0, 0, 0, 0, 0};
  for (int k0 = 0; k0 < K; k0 += 160) {
#pragma unroll
    for (int i = 0; i < 5; i++) {
      int u = tid + i * 256;            // 0..1279
      int row = u / 20, seg = u - row * 20;
      int k = k0 + seg * 8;
      int m = m0 + row;
      short8 av = vzero;
      if (m < M && k < K) {
        if (a32) {
          const float* Af = (const float*)Ap;
          float4 f0 = *(const float4*)(Af + (size_t)m * K + k);
          float4 f1 = *(const float4*)(Af + (size_t)m * K + k + 4);
          av[0] = (short)f2bf(f0.x); av[1] = (short)f2bf(f0.y);
          av[2] = (short)f2bf(f0.z); av[3] = (short)f2bf(f0.w);
          av[4] = (short)f2bf(f1.x); av[5] = (short)f2bf(f1.y);
          av[6] = (short)f2bf(f1.z); av[7] = (short)f2bf(f1.w);
        } else {
          av = *(const short8*)((const unsigned short*)Ap + (size_t)m * K + k);
        }
      }
      *(short8*)&As[row][seg * 8] = av;
      int n = n0 + row;
      short8 bv = vzero;
      if (n < N && k < K) bv = *(const short8*)(Bt + (size_t)n * K + k);
      *(short8*)&Bs[row][seg * 8] = bv;
    }
    __syncthreads();
#pragma unroll
    for (int kk = 0; kk < 5; kk++) {
      int kq2 = kk * 32 + quad * 8;
      short8 af = *(short8*)&As[wv * 16 + col][kq2];
#pragma unroll
      for (int j = 0; j < 4; j++) {
        short8 bfr = *(short8*)&Bs[j * 16 + col][kq2];
        acc[j] = __builtin_amdgcn_mfma_f32_16x16x32_bf16(af, bfr, acc[j], 0, 0, 0);
      }
    }
    __syncthreads();
  }
#pragma unroll
  for (int j = 0; j < 4; j++) {
    int n = n0 + j * 16 + col;
    if (n >= N) continue;
    float bv = bias ? bias[n] : 0.f;
#pragma unroll
    for (int r = 0; r < 4; r++) {
      int m = m0 + wv * 16 + quad * 4 + r;
      if (m < M) {
        float v = acc[j][r] + bv;
        if (omode == 2) {
          int bq = m >> 10, hw = m & 1023;
          size_t oi = ((size_t)bq * N + n) * 1024 + hw;
          ((float*)outp)[oi] = v + res[oi];
        } else {
          if (res) v += res[(size_t)m * N + n];
          if (omode == 1) ((unsigned short*)outp)[(size_t)m * N + n] = f2bf(v);
          else ((float*)outp)[(size_t)m * N + n] = v;
        }
      }
    }
  }
}

// ---------------- split-K MFMA flash attention: 1024 keys, 4 splits of 256 ----------------
#define VSTR 72
__global__ __launch_bounds__(256) void mfattns_kernel(const unsigned short* __restrict__ qp, int qstr,
                                                      const unsigned short* __restrict__ kp, int kstr,
                                                      const unsigned short* __restrict__ vp, int vstr,
                                                      const float* __restrict__ bias,
                                                      float* __restrict__ Opart,
                                                      float* __restrict__ mpart,
                                                      float* __restrict__ lpart) {
  __shared__ unsigned short Ks[64 * 56];
  __shared__ unsigned short Vt[48 * VSTR];
  __shared__ unsigned short Ps[4][16 * 72];
  int tid = threadIdx.x;
  int lane = tid & 63;
  int wv = tid >> 6;
  int quad = lane >> 4;
  int col = lane & 15;
  int bid = blockIdx.x;
  int split = bid & 3;
  int qt = (bid >> 2) & 15;
  int h = (bid >> 6) & 7;
  int b = bid >> 9;

  short8 zero8 = {0, 0, 0, 0, 0, 0, 0, 0};
  int qrow = qt * 64 + wv * 16 + col;
  const unsigned short* qbase = qp + (size_t)(b * 1024 + qrow) * qstr + h * DH;
  short8 qf0 = *(const short8*)(qbase + quad * 8);
  short8 qf1 = (quad == 0) ? *(const short8*)(qbase + 32) : zero8;

  float4v Oacc[3];
  float4v fzero = {0.f, 0.f, 0.f, 0.f};
  Oacc[0] = fzero; Oacc[1] = fzero; Oacc[2] = fzero;
  float mr[4] = {-3.4e38f, -3.4e38f, -3.4e38f, -3.4e38f};
  float lr[4] = {0.f, 0.f, 0.f, 0.f};

  for (int kt = split * 4; kt < split * 4 + 4; kt++) {
    int kb = kt * 64;
    __syncthreads();
    for (int u = tid; u < 384; u += 256) {
      int key = u / 6, s = u - key * 6;
      short8 kv8 = zero8;
      if (s < 5) kv8 = *(const short8*)(kp + (size_t)(b * 1024 + kb + key) * kstr + h * DH + s * 8);
      *(short8*)&Ks[key * 56 + s * 8] = kv8;
    }
    for (int u = tid; u < 384; u += 256) {
      int s = u >> 6, key = u & 63;
      short8 vv8 = zero8;
      if (s < 5) vv8 = *(const short8*)(vp + (size_t)(b * 1024 + kb + key) * vstr + h * DH + s * 8);
#pragma unroll
      for (int j = 0; j < 8; j++) Vt[(s * 8 + j) * VSTR + key] = (unsigned short)vv8[j];
    }
    __syncthreads();

    float4v sf[4];
#pragma unroll
    for (int jb = 0; jb < 4; jb++) {
      const unsigned short* krow = &Ks[(jb * 16 + col) * 56];
      short8 bk0 = *(const short8*)(krow + quad * 8);
      short8 bk1 = (quad == 0) ? *(const short8*)(krow + 32) : zero8;
      float4v s = fzero;
      s = __builtin_amdgcn_mfma_f32_16x16x32_bf16(qf0, bk0, s, 0, 0, 0);
      s = __builtin_amdgcn_mfma_f32_16x16x32_bf16(qf1, bk1, s, 0, 0, 0);
      float bv = bias ? bias[b * 1024 + kb + jb * 16 + col] : 0.f;
#pragma unroll
      for (int r = 0; r < 4; r++) s[r] = s[r] * SCALE + bv;
      sf[jb] = s;
    }
    float tmax[4];
#pragma unroll
    for (int r = 0; r < 4; r++) {
      float t = fmaxf(fmaxf(sf[0][r], sf[1][r]), fmaxf(sf[2][r], sf[3][r]));
#pragma unroll
      for (int o = 1; o < 16; o <<= 1) t = fmaxf(t, __shfl_xor(t, o));
      tmax[r] = t;
    }
    float al[4];
#pragma unroll
    for (int r = 0; r < 4; r++) {
      float mnew = fmaxf(mr[r], tmax[r]);
      al[r] = __expf(mr[r] - mnew);
      mr[r] = mnew;
      lr[r] *= al[r];
    }
#pragma unroll
    for (int nb = 0; nb < 3; nb++)
#pragma unroll
      for (int r = 0; r < 4; r++) Oacc[nb][r] *= al[r];
    float rs[4] = {0.f, 0.f, 0.f, 0.f};
#pragma unroll
    for (int jb = 0; jb < 4; jb++) {
#pragma unroll
      for (int r = 0; r < 4; r++) {
        float p = __expf(sf[jb][r] - mr[r]);
        rs[r] += p;
        Ps[wv][(quad * 4 + r) * 72 + jb * 16 + col] = f2bf(p);
      }
    }
#pragma unroll
    for (int r = 0; r < 4; r++) {
      float t = rs[r];
#pragma unroll
      for (int o = 1; o < 16; o <<= 1) t += __shfl_xor(t, o);
      lr[r] += t;
    }
#pragma unroll
    for (int kc = 0; kc < 2; kc++) {
      int koff = kc * 32 + quad * 8;
      short8 pa = *(const short8*)&Ps[wv][col * 72 + koff];
#pragma unroll
      for (int nb = 0; nb < 3; nb++) {
        short8 vb = *(const short8*)&Vt[(nb * 16 + col) * VSTR + koff];
        Oacc[nb] = __builtin_amdgcn_mfma_f32_16x16x32_bf16(pa, vb, Oacc[nb], 0, 0, 0);
      }
    }
  }
#pragma unroll
  for (int r = 0; r < 4; r++) {
    int qo = qt * 64 + wv * 16 + quad * 4 + r;
    size_t rowidx = (size_t)(b * NH + h) * 1024 + qo;
    float* orow = Opart + (rowidx * 4 + split) * DH;
#pragma unroll
    for (int nb = 0; nb < 3; nb++) {
      int d = nb * 16 + col;
      if (d < DH) orow[d] = Oacc[nb][r];
    }
    if (col == 0) {
      mpart[rowidx * 4 + split] = mr[r];
      lpart[rowidx * 4 + split] = lr[r];
    }
  }
}

// merge 4 split partials -> bf16 rows (attb16 layout, stride 320)
__global__ __launch_bounds__(256) void merge_kernel(const float* __restrict__ Opart,
                                                    const float* __restrict__ mpart,
                                                    const float* __restrict__ lpart,
                                                    unsigned short* __restrict__ op, int rows) {
  int r = blockIdx.x * 256 + threadIdx.x;
  if (r >= rows) return;
  float m0 = mpart[r * 4 + 0], m1 = mpart[r * 4 + 1], m2 = mpart[r * 4 + 2], m3 = mpart[r * 4 + 3];
  float M = fmaxf(fmaxf(m0, m1), fmaxf(m2, m3));
  float w0 = __expf(m0 - M), w1 = __expf(m1 - M), w2 = __expf(m2 - M), w3 = __expf(m3 - M);
  float L = lpart[r * 4 + 0] * w0 + lpart[r * 4 + 1] * w1 + lpart[r * 4 + 2] * w2 + lpart[r * 4 + 3] * w3;
  float inv = 1.f / L;
  w0 *= inv; w1 *= inv; w2 *= inv; w3 *= inv;
  int q = r & 1023;
  int h = (r >> 10) & 7;
  int b = r >> 13;
  const float4* p0 = (const float4*)(Opart + (size_t)(r * 4 + 0) * DH);
  const float4* p1 = (const float4*)(Opart + (size_t)(r * 4 + 1) * DH);
  const float4* p2 = (const float4*)(Opart + (size_t)(r * 4 + 2) * DH);
  const float4* p3 = (const float4*)(Opart + (size_t)(r * 4 + 3) * DH);
  unsigned short* o = op + ((size_t)(b * 1024 + q)) * 320 + h * DH;
#pragma unroll
  for (int j = 0; j < 10; j++) {
    float4 a = p0[j], bb = p1[j], c = p2[j], d = p3[j];
    ushort4 pk;
    pk.x = f2bf(a.x * w0 + bb.x * w1 + c.x * w2 + d.x * w3);
    pk.y = f2bf(a.y * w0 + bb.y * w1 + c.y * w2 + d.y * w3);
    pk.z = f2bf(a.z * w0 + bb.z * w1 + c.z * w2 + d.z * w3);
    pk.w = f2bf(a.w * w0 + bb.w * w1 + c.w * w2 + d.w * w3);
    *(ushort4*)(o + j * 4) = pk;
  }
}

// ---------------- MFMA cross-attention Lk=77 (bf16 in, bf16 out, f32 probs) ----------------
#define CVSTR 104
__global__ __launch_bounds__(256) void cattnm_kernel(const unsigned short* __restrict__ qp,
                                                     const unsigned short* __restrict__ kvp,
                                                     unsigned short* __restrict__ op,
                                                     float* __restrict__ probs) {
  __shared__ unsigned short Ks[80 * 56];
  __shared__ unsigned short Vt[48 * CVSTR];
  __shared__ unsigned short Ps[4][16 * 104];
  int tid = threadIdx.x;
  int lane = tid & 63;
  int wv = tid >> 6;
  int quad = lane >> 4;
  int col = lane & 15;
  int bid = blockIdx.x;
  int qt = bid & 15;
  int h = (bid >> 4) & 7;
  int b = bid >> 7;

  short8 zero8 = {0, 0, 0, 0, 0, 0, 0, 0};
  for (int u = tid; u < 480; u += 256) {
    int key = u / 6, s = u - key * 6;
    short8 v8 = zero8;
    if (s < 5 && key < 77) v8 = *(const short8*)(kvp + (size_t)(b * 77 + key) * 640 + h * DH + s * 8);
    *(short8*)&Ks[key * 56 + s * 8] = v8;
  }
  for (int u = tid; u < 576; u += 256) {
    int s = u / 96, key = u - s * 96;
    short8 v8 = zero8;
    if (s < 5 && key < 77) v8 = *(const short8*)(kvp + (size_t)(b * 77 + key) * 640 + 320 + h * DH + s * 8);
#pragma unroll
    for (int j = 0; j < 8; j++) Vt[(s * 8 + j) * CVSTR + key] = (unsigned short)v8[j];
  }
  int qrow = qt * 64 + wv * 16 + col;
  const unsigned short* qbase = qp + (size_t)(b * 1024 + qrow) * CCH + h * DH;
  short8 qf0 = *(const short8*)(qbase + quad * 8);
  short8 qf1 = (quad == 0) ? *(const short8*)(qbase + 32) : zero8;
  __syncthreads();

  float4v fzero = {0.f, 0.f, 0.f, 0.f};
  float4v sf[5];
#pragma unroll
  for (int jb = 0; jb < 5; jb++) {
    const unsigned short* krow = &Ks[(jb * 16 + col) * 56];
    short8 bk0 = *(const short8*)(krow + quad * 8);
    short8 bk1 = (quad == 0) ? *(const short8*)(krow + 32) : zero8;
    float4v s = fzero;
    s = __builtin_amdgcn_mfma_f32_16x16x32_bf16(qf0, bk0, s, 0, 0, 0);
    s = __builtin_amdgcn_mfma_f32_16x16x32_bf16(qf1, bk1, s, 0, 0, 0);
    int key = jb * 16 + col;
    float msk = (key < 77) ? 0.f : -3.4e38f;
#pragma unroll
    for (int r = 0; r < 4; r++) s[r] = s[r] * SCALE + msk;
    sf[jb] = s;
  }
  float inv[4];
#pragma unroll
  for (int r = 0; r < 4; r++) {
    float t = sf[0][r];
#pragma unroll
    for (int jb = 1; jb < 5; jb++) t = fmaxf(t, sf[jb][r]);
#pragma unroll
    for (int o = 1; o < 16; o <<= 1) t = fmaxf(t, __shfl_xor(t, o));
    float sum = 0.f;
#pragma unroll
    for (int jb = 0; jb < 5; jb++) { float e = __expf(sf[jb][r] - t); sf[jb][r] = e; sum += e; }
#pragma unroll
    for (int o = 1; o < 16; o <<= 1) sum += __shfl_xor(sum, o);
    inv[r] = 1.f / sum;
  }
#pragma unroll
  for (int jb = 0; jb < 5; jb++) {
    int key = jb * 16 + col;
#pragma unroll
    for (int r = 0; r < 4; r++) {
      float p = sf[jb][r] * inv[r];
      Ps[wv][(quad * 4 + r) * 104 + jb * 16 + col] = f2bf(p);
      if (key < 77) {
        int row = qt * 64 + wv * 16 + quad * 4 + r;
        probs[((size_t)(b * NH + h) * 1024 + row) * 77 + key] = p;
      }
    }
  }
  float4v Oacc[3];
  Oacc[0] = fzero; Oacc[1] = fzero; Oacc[2] = fzero;
#pragma unroll
  for (int kc = 0; kc < 3; kc++) {
    int koff = kc * 32 + quad * 8;
    short8 pa = (koff < 80) ? *(const short8*)&Ps[wv][col * 104 + koff] : zero8;
#pragma unroll
    for (int nb = 0; nb < 3; nb++) {
      short8 vb = *(const short8*)&Vt[(nb * 16 + col) * CVSTR + koff];
      Oacc[nb] = __builtin_amdgcn_mfma_f32_16x16x32_bf16(pa, vb, Oacc[nb], 0, 0, 0);
    }
  }
#pragma unroll
  for (int r = 0; r < 4; r++) {
    int qo = qt * 64 + wv * 16 + quad * 4 + r;
    unsigned short* orow = op + (size_t)(b * 1024 + qo) * CCH + h * DH;
#pragma unroll
    for (int nb = 0; nb < 3; nb++) {
      int d = nb * 16 + col;
      if (d < DH) orow[d] = f2bf(Oacc[nb][r]);
    }
  }
}

// ---------------- fused extract + loss + otsu: 2 blocks (one per ph row) ----------------
__global__ __launch_bounds__(256) void eol_kernel(const float* __restrict__ p2,
                                                  const int* __restrict__ phb, const int* __restrict__ pht,
                                                  const int* __restrict__ eob, const int* __restrict__ eot,
                                                  float* __restrict__ mask,
                                                  float* __restrict__ lossout) {
  __shared__ float xs[1024], ys[1024];
  __shared__ float red[256];
  __shared__ float cl[10], sl[10];
  __shared__ float shthr;
  int i = blockIdx.x, tid = threadIdx.x;
  int pb = phb[i], pt = pht[i], eb = eob[i], et = eot[i];
  for (int q = tid; q < 1024; q += 256) {
    float s1 = 0.f, s2 = 0.f;
#pragma unroll
    for (int hh = 0; hh < NH; hh++) {
      s1 += p2[(((size_t)(2 + pb) * NH + hh) * 1024 + q) * 77 + pt];
      s2 += p2[(((size_t)(2 + eb) * NH + hh) * 1024 + q) * 77 + et];
    }
    xs[q] = s1 * 0.125f;
    ys[q] = s2 * 0.125f;
  }
  __syncthreads();
  // --- loss partial (on raw xs/ys) ---
  float mp = -3.4e38f, me = -3.4e38f;
  for (int q = tid; q < 1024; q += 256) { mp = fmaxf(mp, xs[q]); me = fmaxf(me, ys[q]); }
  red[tid] = mp; __syncthreads();
  for (int o = 128; o > 0; o >>= 1) { if (tid < o) red[tid] = fmaxf(red[tid], red[tid + o]); __syncthreads(); }
  mp = red[0]; __syncthreads();
  red[tid] = me; __syncthreads();
  for (int o = 128; o > 0; o >>= 1) { if (tid < o) red[tid] = fmaxf(red[tid], red[tid + o]); __syncthreads(); }
  me = red[0]; __syncthreads();
  float part = 0.f;
  for (int q = tid; q < 1024; q += 256) {
    float d = xs[q] / mp - ys[q] / me;
    part += d * d;
  }
  red[tid] = part; __syncthreads();
  for (int o = 128; o > 0; o >>= 1) { if (tid < o) red[tid] += red[tid + o]; __syncthreads(); }
  if (tid == 0) atomicAdd(lossout, red[0] * (1.f / 2048.f));
  __syncthreads();
  // --- otsu on xs ---
  float mn = 3.4e38f, mx = -3.4e38f;
  for (int q = tid; q < 1024; q += 256) { mn = fminf(mn, xs[q]); mx = fmaxf(mx, xs[q]); }
  red[tid] = mn; __syncthreads();
  for (int o = 128; o > 0; o >>= 1) { if (tid < o) red[tid] = fminf(red[tid], red[tid + o]); __syncthreads(); }
  mn = red[0]; __syncthreads();
  red[tid] = mx; __syncthreads();
  for (int o = 128; o > 0; o >>= 1) { if (tid < o) red[tid] = fmaxf(red[tid], red[tid + o]); __syncthreads(); }
  mx = red[0]; __syncthreads();
  float inv = 1.f / (mx - mn);
  for (int q = tid; q < 1024; q += 256) xs[q] = (xs[q] - mn) * inv;
  __syncthreads();
  float t0 = 0.f;
  for (int q = tid; q < 1024; q += 256) t0 += xs[q];
  red[tid] = t0; __syncthreads();
  for (int o = 128; o > 0; o >>= 1) { if (tid < o) red[tid] += red[tid + o]; __syncthreads(); }
  float total = red[0]; __syncthreads();
  for (int t = 0; t < 10; t++) {
    float th = t * 0.1f;
    float c = 0.f, s = 0.f;
    for (int q = tid; q < 1024; q += 256) { float v = xs[q]; if (v < th) { c += 1.f; s += v; } }
    red[tid] = c; __syncthreads();
    for (int o = 128; o > 0; o >>= 1) { if (tid < o) red[tid] += red[tid + o]; __syncthreads(); }
    if (tid == 0) cl[t] = red[0];
    __syncthreads();
    red[tid] = s; __syncthreads();
    for (int o = 128; o > 0; o >>= 1) { if (tid < o) red[tid] += red[tid + o]; __syncthreads(); }
    if (tid == 0) sl[t] = red[0];
    __syncthreads();
  }
  if (tid == 0) {
    float gmax = -3.4e38f; int best = 0;
    for (int t = 0; t < 10; t++) {
      float c_low = cl[t], c_high = 1024.f - c_low;
      float g;
      if (c_low > 0.f && c_high > 0.f) {
        float mu_l = sl[t] / c_low;
        float mu_h = (total - sl[t]) / c_high;
        float d = mu_l - mu_h;
        g = (c_low * (1.f / 1024.f)) * (c_high * (1.f / 1024.f)) * d * d;
      } else g = -3.4e38f;
      if (g > gmax) { gmax = g; best = t; }
    }
    shthr = (gmax > 0.f) ? best * 0.1f : 0.f;
  }
  __syncthreads();
  float thr = shthr;
  for (int q = tid; q < 1024; q += 256) {
    float v = xs[q];
    mask[i * 1024 + q] = (v < thr) ? 0.f : ((v > thr) ? 1.f : v);
  }
}

extern "C" void kernel_launch(void* const* d_in, const int* in_sizes, int n_in,
                              void* d_out, int out_size, void* d_ws, size_t ws_size,
                              hipStream_t stream) {
  auto F = [&](int i) { return (const float*)d_in[i]; };
  auto I = [&](int i) { return (const int*)d_in[i]; };

  float* ws = (float*)d_ws;
  float* h    = ws;                       // 1310720
  float* ffb  = h    + 1310720;           // attn split partials
  float* p2   = ffb  + 10485760;          // 2523136
  float* mask = p2   + 2523136;           // 2048

  float* Opart = ffb;                       // 32768*4*40 = 5242880
  float* mpart = ffb + 5242880;             // 131072
  float* lpart = ffb + 5242880 + 131072;    // 131072

  // bf16 region
  unsigned short* b16   = (unsigned short*)(mask + 2048);
  unsigned short* lnb16 = b16;                 // 1310720
  unsigned short* attb16= lnb16 + 1310720;     // 1310720
  unsigned short* actb16= attb16 + 1310720;    // 5242880
  unsigned short* qkv16 = actb16 + 5242880;    // 3932160
  unsigned short* q16   = qkv16 + 3932160;     // 1310720
  unsigned short* kv16  = q16 + 1310720;       // 1310720
  unsigned short* wptr  = kv16 + 1310720;

  auto walloc = [&](int n) { unsigned short* p = wptr; wptr += n; return p; };
  unsigned short* pin_t  = walloc(102400);
  unsigned short* bqkv_t = walloc(307200);
  unsigned short* bow_t  = walloc(102400);
  unsigned short* bq2_t  = walloc(102400);
  unsigned short* bkv2_t = walloc(491520);
  unsigned short* bo2_t  = walloc(102400);
  unsigned short* bff1_t = walloc(819200);
  unsigned short* bff2_t = walloc(409600);
  unsigned short* iqkv_t = walloc(307200);
  unsigned short* iow_t  = walloc(102400);
  unsigned short* iq2_t  = walloc(102400);
  unsigned short* ikv2_t = walloc(204800);
  unsigned short* io2_t  = walloc(102400);
  unsigned short* iff1_t = walloc(819200);
  unsigned short* iff2_t = walloc(409600);
  unsigned short* pout_t = walloc(102400);

  float* out = (float*)d_out;

  // --- weight conversion table ---
  WTab wt;
  wt.lz = out + 1310720;   // loss slot zeroed by wconv
  int nt = 0, cnt = 0;
  auto addw = [&](const float* s, unsigned short* d, int K, int N, int perm) {
    wt.src[cnt] = s; wt.dst[cnt] = d; wt.Kd[cnt] = K; wt.Nd[cnt] = N; wt.perm[cnt] = perm;
    wt.tstart[cnt] = nt;
    nt += ((K + 31) / 32) * ((N + 31) / 32);
    cnt++;
  };
  addw(F(2), pin_t, 320, 320, 0);
  addw(F(4 + 2), bqkv_t, 320, 960, 0);
  addw(F(4 + 3), bow_t, 320, 320, 0);
  addw(F(4 + 7), bq2_t, 320, 320, 0);
  addw(F(4 + 8), bkv2_t, 768, 640, 0);
  addw(F(4 + 9), bo2_t, 320, 320, 0);
  addw(F(4 + 13), bff1_t, 320, 2560, 1);
  addw(F(4 + 15), bff2_t, 1280, 320, 0);
  addw(F(21 + 2), iqkv_t, 320, 960, 0);
  addw(F(21 + 3), iow_t, 320, 320, 0);
  addw(F(21 + 7), iq2_t, 320, 320, 0);
  addw(F(21 + 8), ikv2_t, 320, 640, 0);
  addw(F(21 + 9), io2_t, 320, 320, 0);
  addw(F(21 + 13), iff1_t, 320, 2560, 1);
  addw(F(21 + 15), iff2_t, 1280, 320, 0);
  addw(F(38), pout_t, 320, 320, 0);
  wt.tstart[16] = nt;

  wconv_kernel<<<nt, 256, 0, stream>>>(wt);

  auto gemm64 = [&](const void* A, const unsigned short* Wt, const float* bias,
                    const float* res, void* o, int M, int N, int K, int a32, int omode) {
    dim3 g((N + 63) / 64, (M + 63) / 64);
    mgemm64_kernel<<<g, 256, 0, stream>>>(A, Wt, bias, res, o, M, N, K, a32, omode);
  };
  auto gemm128 = [&](const unsigned short* A, const unsigned short* Wt, const float* bias,
                     const float* res, void* o, int M, int N, int K, int obf, int gl) {
    dim3 g((N + 127) / 128, (M + 127) / 128);
    mgemm_kernel<<<g, 256, 0, stream>>>(A, Wt, bias, res, o, M, N, K, obf, gl);
  };

  // GN + transpose -> lnb16 ; pin proj -> h (f32)
  gn_kernel<<<128, 256, 0, stream>>>(F(40), F(0), F(1), lnb16);
  gemm64(lnb16, pin_t, F(3), nullptr, h, 4096, 320, 320, 0, 0);

  auto run_block = [&](int p, int Bx, bool img_block,
                       const unsigned short* qkv_t, const unsigned short* ow_t,
                       const unsigned short* q2_t, const unsigned short* kv2_t,
                       const unsigned short* o2_t, const unsigned short* ff1_t,
                       const unsigned short* ff2_t) {
    int M = Bx * 1024;
    // ln1 -> qkv (bf16) -> split-K mfma flash self-attn -> merge -> o-proj (+res)
    ln_kernel<<<M, 64, 0, stream>>>(h, F(p + 0), F(p + 1), lnb16, M);
    gemm128(lnb16, qkv_t, nullptr, nullptr, qkv16, M, 960, 320, 1, 0);
    mfattns_kernel<<<Bx * 512, 256, 0, stream>>>(qkv16, 960, qkv16 + 320, 960, qkv16 + 640, 960,
                                                 nullptr, Opart, mpart, lpart);
    merge_kernel<<<Bx * 32, 256, 0, stream>>>(Opart, mpart, lpart, attb16, Bx * 8192);
    gemm64(attb16, ow_t, F(p + 4), h, h, M, 320, 320, 0, 0);
    // ln2 -> cross-attn
    ln_kernel<<<M, 64, 0, stream>>>(h, F(p + 5), F(p + 6), lnb16, M);
    if (!img_block) {
      gemm64(F(41), kv2_t, nullptr, nullptr, kv16, Bx * 77, 640, 768, 1, 1);   // f32 A
      gemm64(lnb16, q2_t, nullptr, nullptr, q16, M, 320, 320, 0, 1);
      cattnm_kernel<<<Bx * 128, 256, 0, stream>>>(q16, kv16, attb16, p2);
    } else {
      gemm64(h + (size_t)2 * 1024 * 320, kv2_t, nullptr, nullptr, kv16, Bx * 1024, 640, 320, 1, 1);  // f32 A
      gemm64(lnb16, q2_t, nullptr, nullptr, q16, M, 320, 320, 0, 1);
      mfattns_kernel<<<Bx * 512, 256, 0, stream>>>(q16, 320, kv16, 640, kv16 + 320, 640,
                                                   mask, Opart, mpart, lpart);
      merge_kernel<<<Bx * 32, 256, 0, stream>>>(Opart, mpart, lpart, attb16, Bx * 8192);
    }
    gemm64(attb16, o2_t, F(p + 10), h, h, M, 320, 320, 0, 0);
    // ln3 -> ff1 (fused GEGLU epilogue -> actb16) -> ff2
    ln_kernel<<<M, 64, 0, stream>>>(h, F(p + 11), F(p + 12), lnb16, M);
    gemm128(lnb16, ff1_t, F(p + 14), nullptr, actb16, M, 2560, 320, 1, 1);
    gemm64(actb16, ff2_t, F(p + 16), h, h, M, 320, 1280, 0, 0);
  };

  // Block 1: all 4 batches, ctx = encoder_hidden_states, probs saved
  run_block(4, 4, false, bqkv_t, bow_t, bq2_t, bkv2_t, bo2_t, bff1_t, bff2_t);

  // fused extract + loss + otsu (loss slot zeroed in wconv)
  eol_kernel<<<2, 256, 0, stream>>>(p2, I(42), I(43), I(44), I(45), mask, out + 1310720);

  // Block 2: batches 0-1 in place, ctx = batches 2-3 of h, bias = mask
  run_block(21, 2, true, iqkv_t, iow_t, iq2_t, ikv2_t, io2_t, iff1_t, iff2_t);

  // pout proj with fused transpose + residual epilogue (f32 A = h)
  gemm64(h, pout_t, F(39), F(40), out, 4096, 320, 320, 1, 2);
}